// Round 17
// baseline (4882.889 us; speedup 1.0000x reference)
//
#include <hip/hip_runtime.h>
#include <math.h>

#define NN 40
#define DD 768
#define TT 820   // (N+1)*N/2

typedef unsigned short u16;
typedef __attribute__((ext_vector_type(8))) short bfrag8;
typedef __attribute__((ext_vector_type(4))) float facc4;

__device__ __forceinline__ int ftd(int b, int e) {
    int l = e - b;
    return TT - (NN - l + 2) * (NN - l + 1) / 2 + b;
}
__device__ __forceinline__ float bf2f(u16 u) {
    union { unsigned int i; float f; } x; x.i = ((unsigned)u) << 16; return x.f;
}
__device__ __forceinline__ u16 f2bf(float f) {
    unsigned u = __float_as_uint(f);
    u += 0x7fff + ((u >> 16) & 1);
    return (u16)(u >> 16);
}
// hardware packed f32->bf16 (RNE), lo in [15:0], hi in [31:16]
__device__ __forceinline__ unsigned cvtpk(float lo, float hi) {
    unsigned r;
    asm("v_cvt_pk_bf16_f32 %0, %1, %2" : "=v"(r) : "v"(lo), "v"(hi));
    return r;
}
__device__ __forceinline__ float dot2(unsigned a, unsigned c) {
    return bf2f((u16)a) * bf2f((u16)c) + bf2f((u16)(a >> 16)) * bf2f((u16)(c >> 16));
}

#define GLOAD16(gp, lp) __builtin_amdgcn_global_load_lds( \
    (const __attribute__((address_space(1))) unsigned int*)(gp), \
    (__attribute__((address_space(3))) unsigned int*)(lp), 16, 0, 0)

#define MODE_IN 1
#define MODE_OUT 2

// map pair-row -> (u cell, v cell)
template<int MODE>
__device__ __forceinline__ void pairmap(int r, int g0, int Sps, int level,
                                        int& uc, int& vc, int& bb)
{
    int p = r >> 5; bb = r & 31;
    int g = g0 + p / Sps, si = p % Sps;
    if (MODE == MODE_IN) {
        int s = si + 1;
        uc = ftd(g, g + s); vc = ftd(g + s, g + level);
    } else {
        if (si < g) { uc = ftd(si, g + level); vc = ftd(si, g); }
        else { int c = si + level + 1; uc = ftd(g, c); vc = ftd(g + level, c); }
    }
}

// ---------------- transform: Out{U,V,W}[m] = A[m] @ Wcat-slab^T (+b1 for V slab) ----------------
// 64-row tiles, double-buffered LDS, ONE barrier per K-step (2-phase pipeline).
__global__ __launch_bounds__(256)
void transform_k(const u16* __restrict__ A, const u16* __restrict__ Wcat,
                 u16* __restrict__ OutU, u16* __restrict__ OutV,
                 u16* __restrict__ OutW, const float* __restrict__ bias, int M)
{
    __shared__ __align__(16) u16 As[2][64 * 32];    // 8 KB
    __shared__ __align__(16) u16 Bs[2][128 * 32];   // 16 KB
    const int tid = threadIdx.x, lane = tid & 63, wv = tid >> 6;
    const int m0 = blockIdx.x * 64;
    const int slab = blockIdx.y / 6;
    const int j0 = (blockIdx.y % 6) * 128;
    u16* Out = (slab == 0) ? OutU : (slab == 1 ? OutV : OutW);
    const int NT = DD / 32;             // 24 K-steps

    const int srow = tid >> 2;          // 0..63
    const int kos = (((tid & 3) ^ ((tid >> 3) & 3))) * 8;   // source-side swizzle
    int ar = m0 + srow; if (ar >= M) ar = M - 1;
    const u16* ap = A + (size_t)ar * DD + kos;
    const u16* bq0 = Wcat + (size_t)(slab * DD + j0 + srow) * DD + kos;
    const u16* bq1 = bq0 + (size_t)64 * DD;
    const int aofs = wv * 512;
    const int bofs0 = wv * 512;
    const int bofs1 = 2048 + wv * 512;

    facc4 acc[2][4];
    #pragma unroll
    for (int i = 0; i < 2; ++i)
        #pragma unroll
        for (int j = 0; j < 4; ++j) acc[i][j] = (facc4){0.f, 0.f, 0.f, 0.f};

    const int wr = wv >> 1, wc = wv & 1;
    const int fr = lane & 15;
    const int sk = ((lane >> 4) ^ ((lane >> 1) & 3)) * 8;

    // prologue: stage K-step 0 into buffer 0
    GLOAD16(ap, &As[0][aofs]);
    GLOAD16(bq0, &Bs[0][bofs0]);
    GLOAD16(bq1, &Bs[0][bofs1]);
    __syncthreads();

    for (int t = 0; t < NT; ++t) {
        const int cur = t & 1;
        if (t + 1 < NT) {
            GLOAD16(ap + (t + 1) * 32, &As[cur ^ 1][aofs]);
            GLOAD16(bq0 + (t + 1) * 32, &Bs[cur ^ 1][bofs0]);
            GLOAD16(bq1 + (t + 1) * 32, &Bs[cur ^ 1][bofs1]);
        }
        bfrag8 a[2], b[4];
        #pragma unroll
        for (int fi = 0; fi < 2; ++fi)
            a[fi] = *(const bfrag8*)&As[cur][(wr * 32 + fi * 16 + fr) * 32 + sk];
        #pragma unroll
        for (int fj = 0; fj < 4; ++fj)
            b[fj] = *(const bfrag8*)&Bs[cur][(wc * 64 + fj * 16 + fr) * 32 + sk];
        __builtin_amdgcn_s_setprio(1);
        #pragma unroll
        for (int fi = 0; fi < 2; ++fi)
            #pragma unroll
            for (int fj = 0; fj < 4; ++fj)
                acc[fi][fj] = __builtin_amdgcn_mfma_f32_16x16x32_bf16(
                    a[fi], b[fj], acc[fi][fj], 0, 0, 0);
        __builtin_amdgcn_s_setprio(0);
        __syncthreads();
    }

    const int r0l = (lane >> 4) * 4;
    #pragma unroll
    for (int fi = 0; fi < 2; ++fi)
        #pragma unroll
        for (int r = 0; r < 4; ++r) {
            int m = m0 + wr * 32 + fi * 16 + r0l + r;
            if (m < M) {
                #pragma unroll
                for (int fj = 0; fj < 4; ++fj) {
                    int n = j0 + wc * 64 + fj * 16 + fr;
                    float vo = acc[fi][fj][r];
                    if (slab == 1) vo += bias[n];   // fold b1 into V
                    Out[(size_t)m * DD + n] = f2bf(vo);
                }
            }
        }
}

// -------- fused level kernel: blocks [0,NG) = UNWEIGHTED gemm2f; blocks [NG,NG+nb*32) = score+softmax --------
template<int MODE>
__global__ __launch_bounds__(512)
void level_k(const u16* __restrict__ Ubase, const u16* __restrict__ Vbase,
             const u16* __restrict__ W2, const float* __restrict__ b2,
             u16* __restrict__ Out, int M, int level, int g0, int Sps, int NG,
             const u16* __restrict__ ivb, const u16* __restrict__ IWb,
             const u16* __restrict__ ovb, float* __restrict__ isc,
             float* __restrict__ osc, float* __restrict__ wbuf, int cellrow0)
{
    __shared__ __align__(16) u16 As[2][128 * 32];   // 16 KB
    __shared__ __align__(16) u16 Bs[2][256 * 32];   // 32 KB
    const int tid = threadIdx.x, lane = tid & 63, wv = tid >> 6;

    if (blockIdx.x >= NG) {
        // ---------------- score + softmax block ----------------
        float* sS = (float*)&As[0][0];
        const int blk = blockIdx.x - NG;      // gl*32 + bb
        const int gl = blk >> 5, bb = blk & 31;
        for (int s = wv; s < Sps; s += 8) {
            const u16 *lp, *rp; float add;
            if (MODE == MODE_IN) {
                int lc = ftd(gl, gl + s + 1), rc = ftd(gl + s + 1, gl + level);
                lp = ivb + (size_t)(lc * 32 + bb) * DD;
                rp = IWb + (size_t)(rc * 32 + bb) * DD;
                add = isc[lc * 32 + bb] + isc[rc * 32 + bb];
            } else {
                int pc, scl;
                if (s < gl) { pc = ftd(s, gl + level); scl = ftd(s, gl); }
                else { int c2 = s + level + 1; pc = ftd(gl, c2); scl = ftd(gl + level, c2); }
                lp = ovb + (size_t)(pc * 32 + bb) * DD;
                rp = IWb + (size_t)(scl * 32 + bb) * DD;
                add = osc[pc * 32 + bb] + isc[scl * 32 + bb];
            }
            float sum = 0.f;
            #pragma unroll
            for (int i = 0; i < 3; ++i) {
                uint2 a = *(const uint2*)(lp + i * 256 + lane * 4);
                uint2 c = *(const uint2*)(rp + i * 256 + lane * 4);
                sum += dot2(a.x, c.x) + dot2(a.y, c.y);
            }
            #pragma unroll
            for (int off = 32; off; off >>= 1) sum += __shfl_xor(sum, off);
            if (lane == 0) sS[s] = sum + add;
        }
        __syncthreads();
        if (wv == 0) {
            bool act = lane < Sps;
            float x = act ? sS[lane] : -3.0e38f;
            float m = x;
            #pragma unroll
            for (int off = 32; off; off >>= 1) m = fmaxf(m, __shfl_xor(m, off));
            float e = act ? expf(x - m) : 0.f;
            float ssum = e;
            #pragma unroll
            for (int off = 32; off; off >>= 1) ssum += __shfl_xor(ssum, off);
            float wt = e / ssum;
            if (act) wbuf[(gl * Sps + lane) * 32 + bb] = wt;
            float ws = act ? wt * x : 0.f;
            #pragma unroll
            for (int off = 32; off; off >>= 1) ws += __shfl_xor(ws, off);
            if (lane == 0) {
                float* scout = (MODE == MODE_IN) ? isc : osc;
                scout[cellrow0 + gl * 32 + bb] = ws;
            }
        }
        return;
    }

    // ---------------- gemm2 block (unweighted) ----------------
    const int q = blockIdx.x;
    const int cxcd = q & 7, tq = q >> 3;
    const int mblk = (tq / 3) * 8 + cxcd;
    const int jt = tq % 3;
    const int m0 = mblk * 128;
    if (m0 >= M) return;                     // uniform early-exit (padding blocks)
    const int j0 = jt * 256;

    const int srow = tid >> 2;          // 0..127
    const int ko = (tid & 3) * 8;
    const int aslot = ((tid & 3) ^ ((tid >> 3) & 3)) * 8;
    const int NT = DD / 32;             // 24 K-steps

    const u16 *u0, *v0;
    {
        int r = m0 + srow; if (r >= M) r = M - 1;
        int uc, vc, bb;
        pairmap<MODE>(r, g0, Sps, level, uc, vc, bb);
        u0 = Ubase + (size_t)(uc * 32 + bb) * DD + ko;
        v0 = Vbase + (size_t)(vc * 32 + bb) * DD + ko;
    }

    const int ksrc = ((lane & 3) ^ ((lane >> 3) & 3)) * 8;
    const int brow0 = wv * 16 + (lane >> 2);
    const u16* bsrc0 = W2 + (size_t)(j0 + brow0) * DD + ksrc;
    const u16* bsrc1 = W2 + (size_t)(j0 + 128 + brow0) * DD + ksrc;
    const int bofs0 = wv * 512;
    const int bofs1 = 4096 + wv * 512;

    facc4 acc[4][4];
    #pragma unroll
    for (int i = 0; i < 4; ++i)
        #pragma unroll
        for (int j = 0; j < 4; ++j) acc[i][j] = (facc4){0.f, 0.f, 0.f, 0.f};

    const int wr = wv >> 2, wc = wv & 3;
    const int fr = lane & 15;
    const int sk = ((lane >> 4) ^ ((lane >> 1) & 3)) * 8;

    GLOAD16(bsrc0, &Bs[0][bofs0]);
    GLOAD16(bsrc1, &Bs[0][bofs1]);
    bfrag8 uc_ = *(const bfrag8*)(u0);
    bfrag8 vc_ = *(const bfrag8*)(v0);
    {
        float f[8];
        #pragma unroll
        for (int j = 0; j < 8; ++j)
            f[j] = fmaxf(bf2f((u16)uc_[j]) + bf2f((u16)vc_[j]), 0.f);
        uint4 pk;
        pk.x = cvtpk(f[0], f[1]); pk.y = cvtpk(f[2], f[3]);
        pk.z = cvtpk(f[4], f[5]); pk.w = cvtpk(f[6], f[7]);
        *(uint4*)&As[0][srow * 32 + aslot] = pk;
    }
    bfrag8 un_ = *(const bfrag8*)(u0 + 32);
    bfrag8 vn_ = *(const bfrag8*)(v0 + 32);
    __syncthreads();

    for (int t = 0; t < NT; ++t) {
        const int cur = t & 1;
        if (t + 1 < NT) {
            GLOAD16(bsrc0 + (t + 1) * 32, &Bs[cur ^ 1][bofs0]);
            GLOAD16(bsrc1 + (t + 1) * 32, &Bs[cur ^ 1][bofs1]);
            float f[8];
            #pragma unroll
            for (int j = 0; j < 8; ++j)
                f[j] = fmaxf(bf2f((u16)un_[j]) + bf2f((u16)vn_[j]), 0.f);
            uint4 pk;
            pk.x = cvtpk(f[0], f[1]); pk.y = cvtpk(f[2], f[3]);
            pk.z = cvtpk(f[4], f[5]); pk.w = cvtpk(f[6], f[7]);
            *(uint4*)&As[cur ^ 1][srow * 32 + aslot] = pk;
            if (t + 2 < NT) {
                un_ = *(const bfrag8*)(u0 + (t + 2) * 32);
                vn_ = *(const bfrag8*)(v0 + (t + 2) * 32);
            }
        }
        bfrag8 a[4], b[4];
        #pragma unroll
        for (int fi = 0; fi < 4; ++fi)
            a[fi] = *(const bfrag8*)&As[cur][(wr * 64 + fi * 16 + fr) * 32 + sk];
        #pragma unroll
        for (int fj = 0; fj < 4; ++fj)
            b[fj] = *(const bfrag8*)&Bs[cur][(wc * 64 + fj * 16 + fr) * 32 + sk];
        __builtin_amdgcn_s_setprio(1);
        #pragma unroll
        for (int fi = 0; fi < 4; ++fi)
            #pragma unroll
            for (int fj = 0; fj < 4; ++fj)
                acc[fi][fj] = __builtin_amdgcn_mfma_f32_16x16x32_bf16(
                    a[fi], b[fj], acc[fi][fj], 0, 0, 0);
        __builtin_amdgcn_s_setprio(0);
        __syncthreads();
    }

    const int r0l = (lane >> 4) * 4;
    #pragma unroll
    for (int fi = 0; fi < 4; ++fi)
        #pragma unroll
        for (int r = 0; r < 4; ++r) {
            int m = m0 + wr * 64 + fi * 16 + r0l + r;
            if (m < M) {
                #pragma unroll
                for (int fj = 0; fj < 4; ++fj) {
                    int n = j0 + wc * 64 + fj * 16 + fr;
                    float v = fmaxf(acc[fi][fj][r] + b2[n], 0.f);  // weight applied in reduce
                    Out[(size_t)m * DD + n] = f2bf(v);
                }
            }
        }
}

// ---------------- weighted reduce over splits (8 cols / thread, 4x unroll) ----------------
__global__ __launch_bounds__(256)
void reduce_k(const u16* __restrict__ v, const float* __restrict__ wbuf,
              u16* __restrict__ chart, int cellrow0, int rows, int Sps)
{
    int idx = blockIdx.x * 256 + threadIdx.x;
    int tot = rows * 96;                       // 96 = 768/8
    if (idx >= tot) return;
    int row = idx / 96, c8 = (idx % 96) * 8;   // row = gl*32+bb
    int gl = row >> 5, bb = row & 31;
    const u16* p = v + ((size_t)(gl * Sps) * 32 + bb) * DD + c8;
    const float* wp = wbuf + (size_t)gl * Sps * 32 + bb;
    const size_t st = (size_t)32 * DD;
    float a0[8] = {}, a1[8] = {}, a2[8] = {}, a3[8] = {};
    int s = 0;
    for (; s + 4 <= Sps; s += 4) {
        bfrag8 x0 = *(const bfrag8*)(p + (size_t)(s + 0) * st);
        bfrag8 x1 = *(const bfrag8*)(p + (size_t)(s + 1) * st);
        bfrag8 x2 = *(const bfrag8*)(p + (size_t)(s + 2) * st);
        bfrag8 x3 = *(const bfrag8*)(p + (size_t)(s + 3) * st);
        float w0 = wp[(size_t)(s + 0) * 32];
        float w1 = wp[(size_t)(s + 1) * 32];
        float w2 = wp[(size_t)(s + 2) * 32];
        float w3 = wp[(size_t)(s + 3) * 32];
        #pragma unroll
        for (int j = 0; j < 8; ++j) {
            a0[j] += w0 * bf2f((u16)x0[j]);
            a1[j] += w1 * bf2f((u16)x1[j]);
            a2[j] += w2 * bf2f((u16)x2[j]);
            a3[j] += w3 * bf2f((u16)x3[j]);
        }
    }
    for (; s < Sps; ++s) {
        bfrag8 x = *(const bfrag8*)(p + (size_t)s * st);
        float w = wp[(size_t)s * 32];
        #pragma unroll
        for (int j = 0; j < 8; ++j) a0[j] += w * bf2f((u16)x[j]);
    }
    #pragma unroll
    for (int j = 0; j < 8; ++j) a0[j] += (a1[j] + a2[j]) + a3[j];
    uint4 pk;
    pk.x = cvtpk(a0[0], a0[1]); pk.y = cvtpk(a0[2], a0[3]);
    pk.z = cvtpk(a0[4], a0[5]); pk.w = cvtpk(a0[6], a0[7]);
    *(uint4*)&chart[(size_t)(cellrow0 + row) * DD + c8] = pk;
}

// ---------------- loss ----------------
__global__ __launch_bounds__(256)
void loss_part(const u16* __restrict__ ovb, const float* __restrict__ base,
               float* __restrict__ lb)
{
    int wid = (blockIdx.x * 256 + threadIdx.x) >> 6;
    int lane = threadIdx.x & 63;
    if (wid >= NN * 32) return;
    const u16* t = ovb + (size_t)wid * DD;
    const float* b = base + (size_t)wid * DD;
    float num = 0, nt = 0, nb = 0;
    #pragma unroll
    for (int i = 0; i < 3; ++i) {
        uint2 a2 = *(const uint2*)(t + i * 256 + lane * 4);
        float4 c = *(const float4*)(b + i * 256 + lane * 4);
        float a0 = bf2f((u16)a2.x), a1 = bf2f((u16)(a2.x >> 16));
        float a2f = bf2f((u16)a2.y), a3 = bf2f((u16)(a2.y >> 16));
        num += a0 * c.x + a1 * c.y + a2f * c.z + a3 * c.w;
        nt  += a0 * a0 + a1 * a1 + a2f * a2f + a3 * a3;
        nb  += c.x * c.x + c.y * c.y + c.z * c.z + c.w * c.w;
    }
    #pragma unroll
    for (int off = 32; off; off >>= 1) {
        num += __shfl_down(num, off);
        nt  += __shfl_down(nt, off);
        nb  += __shfl_down(nb, off);
    }
    if (lane == 0) {
        float den = fmaxf(sqrtf(nt) * sqrtf(nb), 1e-8f);
        lb[wid] = 1.f - num / den;
    }
}

__global__ void loss_fin(const float* __restrict__ lb, float* __restrict__ out)
{
    __shared__ float red[256];
    float s = 0;
    for (int i = threadIdx.x; i < NN * 32; i += 256) s += lb[i];
    red[threadIdx.x] = s;
    __syncthreads();
    for (int o = 128; o; o >>= 1) {
        if (threadIdx.x < o) red[threadIdx.x] += red[threadIdx.x + o];
        __syncthreads();
    }
    if (threadIdx.x == 0) out[0] = red[0] / (NN * 32.f);
}

// ---------------- init helpers ----------------
__global__ void build_wcat(const float* __restrict__ W1, const float* __restrict__ Wbil,
                           u16* __restrict__ Wcat)
{
    int idx = blockIdx.x * 256 + threadIdx.x;
    if (idx >= 2304 * DD) return;
    int r = idx / DD, k = idx % DD;
    float v;
    if (r < 768) v = W1[(size_t)r * 1536 + k];
    else if (r < 1536) v = W1[(size_t)(r - 768) * 1536 + 768 + k];
    else v = Wbil[(size_t)(r - 1536) * DD + k];
    Wcat[idx] = f2bf(v);
}

__global__ void cvt_k(const float* __restrict__ in, u16* __restrict__ out, int n)
{
    int idx = blockIdx.x * 256 + threadIdx.x;
    if (idx < n) out[idx] = f2bf(in[idx]);
}

__global__ void init_rootb(u16* __restrict__ ovb, const float* __restrict__ rb)
{
    int idx = blockIdx.x * 256 + threadIdx.x;
    if (idx < 32 * DD) ovb[(size_t)819 * 32 * DD + idx] = f2bf(rb[idx % DD]);
}

extern "C" void kernel_launch(void* const* d_in, const int* in_sizes, int n_in,
                              void* d_out, int out_size, void* d_ws, size_t ws_size,
                              hipStream_t stream)
{
    const float* base  = (const float*)d_in[0];
    const float* Wbil  = (const float*)d_in[1];
    const float* W1    = (const float*)d_in[2];
    const float* b1    = (const float*)d_in[3];
    const float* W2    = (const float*)d_in[4];
    const float* b2    = (const float*)d_in[5];
    const float* rbias = (const float*)d_in[6];
    float* out = (float*)d_out;

    char* ws = (char*)d_ws;
    size_t off = 0;
    auto alloc = [&](size_t bytes) { size_t o = off; off = (off + bytes + 255) & ~(size_t)255; return o; };
    const size_t SB = (size_t)TT * 32 * DD * 2;   // 40.3 MB bf16 per chart slab
    u16*  ivb = (u16*)(ws + alloc(SB));
    u16*  ovb = (u16*)(ws + alloc(SB));
    u16*  Ub  = (u16*)(ws + alloc(SB));
    u16*  Vb  = (u16*)(ws + alloc(SB));
    u16*  IWb = (u16*)(ws + alloc(SB));
    u16*  Wcat = (u16*)(ws + alloc((size_t)2304 * DD * 2));
    u16*  W2b  = (u16*)(ws + alloc((size_t)DD * DD * 2));
    float* isc = (float*)(ws + alloc((size_t)TT * 32 * 4));
    float* osc = (float*)(ws + alloc((size_t)TT * 32 * 4));
    float* wb  = (float*)(ws + alloc((size_t)1560 * 32 * 4));
    float* lb  = (float*)(ws + alloc((size_t)NN * 32 * 4));
    u16* vin = (u16*)(ws + off);
    size_t vbytes = (ws_size > off) ? (ws_size - off) : 0;

    // --- init ---
    hipMemsetAsync(isc, 0, (size_t)TT * 32 * 4, stream);
    hipMemsetAsync(osc, 0, (size_t)TT * 32 * 4, stream);
    build_wcat<<<(2304 * DD + 255) / 256, 256, 0, stream>>>(W1, Wbil, Wcat);
    cvt_k<<<(DD * DD + 255) / 256, 256, 0, stream>>>(W2, W2b, DD * DD);
    cvt_k<<<(NN * 32 * DD + 255) / 256, 256, 0, stream>>>(base, ivb, NN * 32 * DD);
    init_rootb<<<(32 * DD + 255) / 256, 256, 0, stream>>>(ovb, rbias);
    {   // leaf transforms
        int M = NN * 32;
        dim3 g((M + 63) / 64, 18);
        transform_k<<<g, 256, 0, stream>>>(ivb, Wcat, Ub, Vb, IWb, b1, M);
    }

    auto g2grid = [](int Mc) {
        int xb = (Mc + 127) / 128;
        int XB8 = ((xb + 7) / 8) * 8;
        return 3 * XB8;
    };

    // --- inside pass (L=40 root value unused downstream) ---
    for (int L = 2; L <= NN - 1; ++L) {
        int S = L - 1, nb = NN + 1 - L;
        int cellbase = TT - (NN - L + 2) * (NN - L + 1) / 2;
        size_t perbegin = (size_t)S * 32 * DD * 2;
        int GC = (vbytes >= perbegin) ? (int)(vbytes / perbegin) : 1;
        if (GC < 1) GC = 1;
        if (GC > nb) GC = nb;
        for (int g0 = 0; g0 < nb; g0 += GC) {
            int gc = (g0 + GC <= nb) ? GC : (nb - g0);
            int Mc = gc * S * 32;
            u16* vout = (S == 1) ? (ivb + (size_t)(cellbase + g0) * 32 * DD) : vin;
            int NG = g2grid(Mc);
            int nblk = NG + ((g0 == 0) ? nb * 32 : 0);
            level_k<MODE_IN><<<nblk, 512, 0, stream>>>(
                Ub, Vb, W2b, b2, vout, Mc, L, g0, S, NG,
                ivb, IWb, ovb, isc, osc, wb, cellbase * 32);
            if (S > 1)
                reduce_k<<<(gc * 32 * 96 + 255) / 256, 256, 0, stream>>>(
                    vin, wb + (size_t)g0 * S * 32, ivb, (cellbase + g0) * 32, gc * 32, S);
        }
        {   // transform new cells
            int M = nb * 32;
            dim3 g((M + 63) / 64, 18);
            transform_k<<<g, 256, 0, stream>>>(
                ivb + (size_t)cellbase * 32 * DD, Wcat,
                Ub + (size_t)cellbase * 32 * DD, Vb + (size_t)cellbase * 32 * DD,
                IWb + (size_t)cellbase * 32 * DD, b1, M);
        }
    }

    // --- root u_o ---
    {
        dim3 g(1, 6);
        transform_k<<<g, 256, 0, stream>>>(
            ovb + (size_t)819 * 32 * DD, Wcat,
            Ub + (size_t)819 * 32 * DD, nullptr, nullptr, b1, 32);
    }

    // --- outside pass ---
    for (int L = NN - 1; L >= 1; --L) {
        int S = NN - L, nb = NN + 1 - L;
        int cellbase = TT - (NN - L + 2) * (NN - L + 1) / 2;
        size_t perbegin = (size_t)S * 32 * DD * 2;
        int GC = (vbytes >= perbegin) ? (int)(vbytes / perbegin) : 1;
        if (GC < 1) GC = 1;
        if (GC > nb) GC = nb;
        for (int g0 = 0; g0 < nb; g0 += GC) {
            int gc = (g0 + GC <= nb) ? GC : (nb - g0);
            int Mc = gc * S * 32;
            u16* vout = (S == 1) ? (ovb + (size_t)(cellbase + g0) * 32 * DD) : vin;
            int NG = g2grid(Mc);
            int nblk = NG + ((g0 == 0) ? nb * 32 : 0);
            level_k<MODE_OUT><<<nblk, 512, 0, stream>>>(
                Ub, Vb, W2b, b2, vout, Mc, L, g0, S, NG,
                ivb, IWb, ovb, isc, osc, wb, cellbase * 32);
            if (S > 1)
                reduce_k<<<(gc * 32 * 96 + 255) / 256, 256, 0, stream>>>(
                    vin, wb + (size_t)g0 * S * 32, ovb, (cellbase + g0) * 32, gc * 32, S);
        }
        if (L > 1) {   // u_o for new outside cells
            int M = nb * 32;
            dim3 g((M + 63) / 64, 6);
            transform_k<<<g, 256, 0, stream>>>(
                ovb + (size_t)cellbase * 32 * DD, Wcat,
                Ub + (size_t)cellbase * 32 * DD, nullptr, nullptr, b1, M);
        }
    }

    // --- loss ---
    loss_part<<<(NN * 32 + 3) / 4, 256, 0, stream>>>(ovb, base, lb);
    loss_fin<<<1, 256, 0, stream>>>(lb, out);
}

// Round 18
// 4809.349 us; speedup vs baseline: 1.0153x; 1.0153x over previous
//
#include <hip/hip_runtime.h>
#include <math.h>

#define NN 40
#define DD 768
#define TT 820   // (N+1)*N/2

typedef unsigned short u16;
typedef __attribute__((ext_vector_type(8))) short bfrag8;
typedef __attribute__((ext_vector_type(4))) float facc4;

__device__ __forceinline__ int ftd(int b, int e) {
    int l = e - b;
    return TT - (NN - l + 2) * (NN - l + 1) / 2 + b;
}
__device__ __forceinline__ float bf2f(u16 u) {
    union { unsigned int i; float f; } x; x.i = ((unsigned)u) << 16; return x.f;
}
__device__ __forceinline__ u16 f2bf(float f) {
    unsigned u = __float_as_uint(f);
    u += 0x7fff + ((u >> 16) & 1);
    return (u16)(u >> 16);
}
// hardware packed f32->bf16 (RNE), lo in [15:0], hi in [31:16]
__device__ __forceinline__ unsigned cvtpk(float lo, float hi) {
    unsigned r;
    asm("v_cvt_pk_bf16_f32 %0, %1, %2" : "=v"(r) : "v"(lo), "v"(hi));
    return r;
}
__device__ __forceinline__ float dot2(unsigned a, unsigned c) {
    return bf2f((u16)a) * bf2f((u16)c) + bf2f((u16)(a >> 16)) * bf2f((u16)(c >> 16));
}

#define GLOAD16(gp, lp) __builtin_amdgcn_global_load_lds( \
    (const __attribute__((address_space(1))) unsigned int*)(gp), \
    (__attribute__((address_space(3))) unsigned int*)(lp), 16, 0, 0)

#define MODE_IN 1
#define MODE_OUT 2

// map pair-row -> (u cell, v cell)
template<int MODE>
__device__ __forceinline__ void pairmap(int r, int g0, int Sps, int level,
                                        int& uc, int& vc, int& bb)
{
    int p = r >> 5; bb = r & 31;
    int g = g0 + p / Sps, si = p % Sps;
    if (MODE == MODE_IN) {
        int s = si + 1;
        uc = ftd(g, g + s); vc = ftd(g + s, g + level);
    } else {
        if (si < g) { uc = ftd(si, g + level); vc = ftd(si, g); }
        else { int c = si + level + 1; uc = ftd(g, c); vc = ftd(g + level, c); }
    }
}

// ---------------- transform: Out{U,V,W}[m] = A[m] @ Wcat-slab^T (+b1 for V slab) ----------------
// 64-row tiles, double-buffered LDS, ONE barrier per K-step (2-phase pipeline).
__global__ __launch_bounds__(256)
void transform_k(const u16* __restrict__ A, const u16* __restrict__ Wcat,
                 u16* __restrict__ OutU, u16* __restrict__ OutV,
                 u16* __restrict__ OutW, const float* __restrict__ bias, int M)
{
    __shared__ __align__(16) u16 As[2][64 * 32];    // 8 KB
    __shared__ __align__(16) u16 Bs[2][128 * 32];   // 16 KB
    const int tid = threadIdx.x, lane = tid & 63, wv = tid >> 6;
    const int m0 = blockIdx.x * 64;
    const int slab = blockIdx.y / 6;
    const int j0 = (blockIdx.y % 6) * 128;
    u16* Out = (slab == 0) ? OutU : (slab == 1 ? OutV : OutW);
    const int NT = DD / 32;             // 24 K-steps

    const int srow = tid >> 2;          // 0..63
    const int kos = (((tid & 3) ^ ((tid >> 3) & 3))) * 8;   // source-side swizzle
    int ar = m0 + srow; if (ar >= M) ar = M - 1;
    const u16* ap = A + (size_t)ar * DD + kos;
    const u16* bq0 = Wcat + (size_t)(slab * DD + j0 + srow) * DD + kos;
    const u16* bq1 = bq0 + (size_t)64 * DD;
    const int aofs = wv * 512;
    const int bofs0 = wv * 512;
    const int bofs1 = 2048 + wv * 512;

    facc4 acc[2][4];
    #pragma unroll
    for (int i = 0; i < 2; ++i)
        #pragma unroll
        for (int j = 0; j < 4; ++j) acc[i][j] = (facc4){0.f, 0.f, 0.f, 0.f};

    const int wr = wv >> 1, wc = wv & 1;
    const int fr = lane & 15;
    const int sk = ((lane >> 4) ^ ((lane >> 1) & 3)) * 8;

    // prologue: stage K-step 0 into buffer 0
    GLOAD16(ap, &As[0][aofs]);
    GLOAD16(bq0, &Bs[0][bofs0]);
    GLOAD16(bq1, &Bs[0][bofs1]);
    __syncthreads();

    for (int t = 0; t < NT; ++t) {
        const int cur = t & 1;
        if (t + 1 < NT) {
            GLOAD16(ap + (t + 1) * 32, &As[cur ^ 1][aofs]);
            GLOAD16(bq0 + (t + 1) * 32, &Bs[cur ^ 1][bofs0]);
            GLOAD16(bq1 + (t + 1) * 32, &Bs[cur ^ 1][bofs1]);
        }
        bfrag8 a[2], b[4];
        #pragma unroll
        for (int fi = 0; fi < 2; ++fi)
            a[fi] = *(const bfrag8*)&As[cur][(wr * 32 + fi * 16 + fr) * 32 + sk];
        #pragma unroll
        for (int fj = 0; fj < 4; ++fj)
            b[fj] = *(const bfrag8*)&Bs[cur][(wc * 64 + fj * 16 + fr) * 32 + sk];
        #pragma unroll
        for (int fi = 0; fi < 2; ++fi)
            #pragma unroll
            for (int fj = 0; fj < 4; ++fj)
                acc[fi][fj] = __builtin_amdgcn_mfma_f32_16x16x32_bf16(
                    a[fi], b[fj], acc[fi][fj], 0, 0, 0);
        __syncthreads();
    }

    const int r0l = (lane >> 4) * 4;
    #pragma unroll
    for (int fi = 0; fi < 2; ++fi)
        #pragma unroll
        for (int r = 0; r < 4; ++r) {
            int m = m0 + wr * 32 + fi * 16 + r0l + r;
            if (m < M) {
                #pragma unroll
                for (int fj = 0; fj < 4; ++fj) {
                    int n = j0 + wc * 64 + fj * 16 + fr;
                    float vo = acc[fi][fj][r];
                    if (slab == 1) vo += bias[n];   // fold b1 into V
                    Out[(size_t)m * DD + n] = f2bf(vo);
                }
            }
        }
}

// -------- fused level kernel: blocks [0,NG) = UNWEIGHTED gemm2f; blocks [NG,NG+nb*32) = score+softmax --------
template<int MODE>
__global__ __launch_bounds__(512)
void level_k(const u16* __restrict__ Ubase, const u16* __restrict__ Vbase,
             const u16* __restrict__ W2, const float* __restrict__ b2,
             u16* __restrict__ Out, int M, int level, int g0, int Sps, int NG,
             const u16* __restrict__ ivb, const u16* __restrict__ IWb,
             const u16* __restrict__ ovb, float* __restrict__ isc,
             float* __restrict__ osc, float* __restrict__ wbuf, int cellrow0)
{
    __shared__ __align__(16) u16 As[2][128 * 32];   // 16 KB
    __shared__ __align__(16) u16 Bs[2][256 * 32];   // 32 KB
    const int tid = threadIdx.x, lane = tid & 63, wv = tid >> 6;

    if (blockIdx.x >= NG) {
        // ---------------- score + softmax block ----------------
        float* sS = (float*)&As[0][0];
        const int blk = blockIdx.x - NG;      // gl*32 + bb
        const int gl = blk >> 5, bb = blk & 31;
        for (int s = wv; s < Sps; s += 8) {
            const u16 *lp, *rp; float add;
            if (MODE == MODE_IN) {
                int lc = ftd(gl, gl + s + 1), rc = ftd(gl + s + 1, gl + level);
                lp = ivb + (size_t)(lc * 32 + bb) * DD;
                rp = IWb + (size_t)(rc * 32 + bb) * DD;
                add = isc[lc * 32 + bb] + isc[rc * 32 + bb];
            } else {
                int pc, scl;
                if (s < gl) { pc = ftd(s, gl + level); scl = ftd(s, gl); }
                else { int c2 = s + level + 1; pc = ftd(gl, c2); scl = ftd(gl + level, c2); }
                lp = ovb + (size_t)(pc * 32 + bb) * DD;
                rp = IWb + (size_t)(scl * 32 + bb) * DD;
                add = osc[pc * 32 + bb] + isc[scl * 32 + bb];
            }
            float sum = 0.f;
            #pragma unroll
            for (int i = 0; i < 3; ++i) {
                uint2 a = *(const uint2*)(lp + i * 256 + lane * 4);
                uint2 c = *(const uint2*)(rp + i * 256 + lane * 4);
                sum += dot2(a.x, c.x) + dot2(a.y, c.y);
            }
            #pragma unroll
            for (int off = 32; off; off >>= 1) sum += __shfl_xor(sum, off);
            if (lane == 0) sS[s] = sum + add;
        }
        __syncthreads();
        if (wv == 0) {
            bool act = lane < Sps;
            float x = act ? sS[lane] : -3.0e38f;
            float m = x;
            #pragma unroll
            for (int off = 32; off; off >>= 1) m = fmaxf(m, __shfl_xor(m, off));
            float e = act ? expf(x - m) : 0.f;
            float ssum = e;
            #pragma unroll
            for (int off = 32; off; off >>= 1) ssum += __shfl_xor(ssum, off);
            float wt = e / ssum;
            if (act) wbuf[(gl * Sps + lane) * 32 + bb] = wt;
            float ws = act ? wt * x : 0.f;
            #pragma unroll
            for (int off = 32; off; off >>= 1) ws += __shfl_xor(ws, off);
            if (lane == 0) {
                float* scout = (MODE == MODE_IN) ? isc : osc;
                scout[cellrow0 + gl * 32 + bb] = ws;
            }
        }
        return;
    }

    // ---------------- gemm2 block (unweighted) ----------------
    const int q = blockIdx.x;
    const int cxcd = q & 7, tq = q >> 3;
    const int mblk = (tq / 3) * 8 + cxcd;
    const int jt = tq % 3;
    const int m0 = mblk * 128;
    if (m0 >= M) return;                     // uniform early-exit (padding blocks)
    const int j0 = jt * 256;

    const int srow = tid >> 2;          // 0..127
    const int ko = (tid & 3) * 8;
    const int aslot = ((tid & 3) ^ ((tid >> 3) & 3)) * 8;
    const int NT = DD / 32;             // 24 K-steps

    const u16 *u0, *v0;
    {
        int r = m0 + srow; if (r >= M) r = M - 1;
        int uc, vc, bb;
        pairmap<MODE>(r, g0, Sps, level, uc, vc, bb);
        u0 = Ubase + (size_t)(uc * 32 + bb) * DD + ko;
        v0 = Vbase + (size_t)(vc * 32 + bb) * DD + ko;
    }

    const int ksrc = ((lane & 3) ^ ((lane >> 3) & 3)) * 8;
    const int brow0 = wv * 16 + (lane >> 2);
    const u16* bsrc0 = W2 + (size_t)(j0 + brow0) * DD + ksrc;
    const u16* bsrc1 = W2 + (size_t)(j0 + 128 + brow0) * DD + ksrc;
    const int bofs0 = wv * 512;
    const int bofs1 = 4096 + wv * 512;

    facc4 acc[4][4];
    #pragma unroll
    for (int i = 0; i < 4; ++i)
        #pragma unroll
        for (int j = 0; j < 4; ++j) acc[i][j] = (facc4){0.f, 0.f, 0.f, 0.f};

    const int wr = wv >> 2, wc = wv & 3;
    const int fr = lane & 15;
    const int sk = ((lane >> 4) ^ ((lane >> 1) & 3)) * 8;

    GLOAD16(bsrc0, &Bs[0][bofs0]);
    GLOAD16(bsrc1, &Bs[0][bofs1]);
    bfrag8 uc_ = *(const bfrag8*)(u0);
    bfrag8 vc_ = *(const bfrag8*)(v0);
    {
        float f[8];
        #pragma unroll
        for (int j = 0; j < 8; ++j)
            f[j] = fmaxf(bf2f((u16)uc_[j]) + bf2f((u16)vc_[j]), 0.f);
        uint4 pk;
        pk.x = cvtpk(f[0], f[1]); pk.y = cvtpk(f[2], f[3]);
        pk.z = cvtpk(f[4], f[5]); pk.w = cvtpk(f[6], f[7]);
        *(uint4*)&As[0][srow * 32 + aslot] = pk;
    }
    bfrag8 un_ = *(const bfrag8*)(u0 + 32);
    bfrag8 vn_ = *(const bfrag8*)(v0 + 32);
    __syncthreads();

    for (int t = 0; t < NT; ++t) {
        const int cur = t & 1;
        if (t + 1 < NT) {
            GLOAD16(bsrc0 + (t + 1) * 32, &Bs[cur ^ 1][bofs0]);
            GLOAD16(bsrc1 + (t + 1) * 32, &Bs[cur ^ 1][bofs1]);
            float f[8];
            #pragma unroll
            for (int j = 0; j < 8; ++j)
                f[j] = fmaxf(bf2f((u16)un_[j]) + bf2f((u16)vn_[j]), 0.f);
            uint4 pk;
            pk.x = cvtpk(f[0], f[1]); pk.y = cvtpk(f[2], f[3]);
            pk.z = cvtpk(f[4], f[5]); pk.w = cvtpk(f[6], f[7]);
            *(uint4*)&As[cur ^ 1][srow * 32 + aslot] = pk;
            if (t + 2 < NT) {
                un_ = *(const bfrag8*)(u0 + (t + 2) * 32);
                vn_ = *(const bfrag8*)(v0 + (t + 2) * 32);
            }
        }
        bfrag8 a[4], b[4];
        #pragma unroll
        for (int fi = 0; fi < 4; ++fi)
            a[fi] = *(const bfrag8*)&As[cur][(wr * 64 + fi * 16 + fr) * 32 + sk];
        #pragma unroll
        for (int fj = 0; fj < 4; ++fj)
            b[fj] = *(const bfrag8*)&Bs[cur][(wc * 64 + fj * 16 + fr) * 32 + sk];
        #pragma unroll
        for (int fi = 0; fi < 4; ++fi)
            #pragma unroll
            for (int fj = 0; fj < 4; ++fj)
                acc[fi][fj] = __builtin_amdgcn_mfma_f32_16x16x32_bf16(
                    a[fi], b[fj], acc[fi][fj], 0, 0, 0);
        __syncthreads();
    }

    const int r0l = (lane >> 4) * 4;
    #pragma unroll
    for (int fi = 0; fi < 4; ++fi)
        #pragma unroll
        for (int r = 0; r < 4; ++r) {
            int m = m0 + wr * 64 + fi * 16 + r0l + r;
            if (m < M) {
                #pragma unroll
                for (int fj = 0; fj < 4; ++fj) {
                    int n = j0 + wc * 64 + fj * 16 + fr;
                    float v = fmaxf(acc[fi][fj][r] + b2[n], 0.f);  // weight applied in reduce
                    Out[(size_t)m * DD + n] = f2bf(v);
                }
            }
        }
}

// ---------------- weighted reduce over splits (8 cols / thread, 4x unroll) ----------------
__global__ __launch_bounds__(256)
void reduce_k(const u16* __restrict__ v, const float* __restrict__ wbuf,
              u16* __restrict__ chart, int cellrow0, int rows, int Sps)
{
    int idx = blockIdx.x * 256 + threadIdx.x;
    int tot = rows * 96;                       // 96 = 768/8
    if (idx >= tot) return;
    int row = idx / 96, c8 = (idx % 96) * 8;   // row = gl*32+bb
    int gl = row >> 5, bb = row & 31;
    const u16* p = v + ((size_t)(gl * Sps) * 32 + bb) * DD + c8;
    const float* wp = wbuf + (size_t)gl * Sps * 32 + bb;
    const size_t st = (size_t)32 * DD;
    float a0[8] = {}, a1[8] = {}, a2[8] = {}, a3[8] = {};
    int s = 0;
    for (; s + 4 <= Sps; s += 4) {
        bfrag8 x0 = *(const bfrag8*)(p + (size_t)(s + 0) * st);
        bfrag8 x1 = *(const bfrag8*)(p + (size_t)(s + 1) * st);
        bfrag8 x2 = *(const bfrag8*)(p + (size_t)(s + 2) * st);
        bfrag8 x3 = *(const bfrag8*)(p + (size_t)(s + 3) * st);
        float w0 = wp[(size_t)(s + 0) * 32];
        float w1 = wp[(size_t)(s + 1) * 32];
        float w2 = wp[(size_t)(s + 2) * 32];
        float w3 = wp[(size_t)(s + 3) * 32];
        #pragma unroll
        for (int j = 0; j < 8; ++j) {
            a0[j] += w0 * bf2f((u16)x0[j]);
            a1[j] += w1 * bf2f((u16)x1[j]);
            a2[j] += w2 * bf2f((u16)x2[j]);
            a3[j] += w3 * bf2f((u16)x3[j]);
        }
    }
    for (; s < Sps; ++s) {
        bfrag8 x = *(const bfrag8*)(p + (size_t)s * st);
        float w = wp[(size_t)s * 32];
        #pragma unroll
        for (int j = 0; j < 8; ++j) a0[j] += w * bf2f((u16)x[j]);
    }
    #pragma unroll
    for (int j = 0; j < 8; ++j) a0[j] += (a1[j] + a2[j]) + a3[j];
    uint4 pk;
    pk.x = cvtpk(a0[0], a0[1]); pk.y = cvtpk(a0[2], a0[3]);
    pk.z = cvtpk(a0[4], a0[5]); pk.w = cvtpk(a0[6], a0[7]);
    *(uint4*)&chart[(size_t)(cellrow0 + row) * DD + c8] = pk;
}

// ---------------- loss ----------------
__global__ __launch_bounds__(256)
void loss_part(const u16* __restrict__ ovb, const float* __restrict__ base,
               float* __restrict__ lb)
{
    int wid = (blockIdx.x * 256 + threadIdx.x) >> 6;
    int lane = threadIdx.x & 63;
    if (wid >= NN * 32) return;
    const u16* t = ovb + (size_t)wid * DD;
    const float* b = base + (size_t)wid * DD;
    float num = 0, nt = 0, nb = 0;
    #pragma unroll
    for (int i = 0; i < 3; ++i) {
        uint2 a2 = *(const uint2*)(t + i * 256 + lane * 4);
        float4 c = *(const float4*)(b + i * 256 + lane * 4);
        float a0 = bf2f((u16)a2.x), a1 = bf2f((u16)(a2.x >> 16));
        float a2f = bf2f((u16)a2.y), a3 = bf2f((u16)(a2.y >> 16));
        num += a0 * c.x + a1 * c.y + a2f * c.z + a3 * c.w;
        nt  += a0 * a0 + a1 * a1 + a2f * a2f + a3 * a3;
        nb  += c.x * c.x + c.y * c.y + c.z * c.z + c.w * c.w;
    }
    #pragma unroll
    for (int off = 32; off; off >>= 1) {
        num += __shfl_down(num, off);
        nt  += __shfl_down(nt, off);
        nb  += __shfl_down(nb, off);
    }
    if (lane == 0) {
        float den = fmaxf(sqrtf(nt) * sqrtf(nb), 1e-8f);
        lb[wid] = 1.f - num / den;
    }
}

__global__ void loss_fin(const float* __restrict__ lb, float* __restrict__ out)
{
    __shared__ float red[256];
    float s = 0;
    for (int i = threadIdx.x; i < NN * 32; i += 256) s += lb[i];
    red[threadIdx.x] = s;
    __syncthreads();
    for (int o = 128; o; o >>= 1) {
        if (threadIdx.x < o) red[threadIdx.x] += red[threadIdx.x + o];
        __syncthreads();
    }
    if (threadIdx.x == 0) out[0] = red[0] / (NN * 32.f);
}

// ---------------- init helpers ----------------
__global__ void build_wcat(const float* __restrict__ W1, const float* __restrict__ Wbil,
                           u16* __restrict__ Wcat)
{
    int idx = blockIdx.x * 256 + threadIdx.x;
    if (idx >= 2304 * DD) return;
    int r = idx / DD, k = idx % DD;
    float v;
    if (r < 768) v = W1[(size_t)r * 1536 + k];
    else if (r < 1536) v = W1[(size_t)(r - 768) * 1536 + 768 + k];
    else v = Wbil[(size_t)(r - 1536) * DD + k];
    Wcat[idx] = f2bf(v);
}

__global__ void cvt_k(const float* __restrict__ in, u16* __restrict__ out, int n)
{
    int idx = blockIdx.x * 256 + threadIdx.x;
    if (idx < n) out[idx] = f2bf(in[idx]);
}

__global__ void init_rootb(u16* __restrict__ ovb, const float* __restrict__ rb)
{
    int idx = blockIdx.x * 256 + threadIdx.x;
    if (idx < 32 * DD) ovb[(size_t)819 * 32 * DD + idx] = f2bf(rb[idx % DD]);
}

extern "C" void kernel_launch(void* const* d_in, const int* in_sizes, int n_in,
                              void* d_out, int out_size, void* d_ws, size_t ws_size,
                              hipStream_t stream)
{
    const float* base  = (const float*)d_in[0];
    const float* Wbil  = (const float*)d_in[1];
    const float* W1    = (const float*)d_in[2];
    const float* b1    = (const float*)d_in[3];
    const float* W2    = (const float*)d_in[4];
    const float* b2    = (const float*)d_in[5];
    const float* rbias = (const float*)d_in[6];
    float* out = (float*)d_out;

    char* ws = (char*)d_ws;
    size_t off = 0;
    auto alloc = [&](size_t bytes) { size_t o = off; off = (off + bytes + 255) & ~(size_t)255; return o; };
    const size_t SB = (size_t)TT * 32 * DD * 2;   // 40.3 MB bf16 per chart slab
    u16*  ivb = (u16*)(ws + alloc(SB));
    u16*  ovb = (u16*)(ws + alloc(SB));
    u16*  Ub  = (u16*)(ws + alloc(SB));
    u16*  Vb  = (u16*)(ws + alloc(SB));
    u16*  IWb = (u16*)(ws + alloc(SB));
    u16*  Wcat = (u16*)(ws + alloc((size_t)2304 * DD * 2));
    u16*  W2b  = (u16*)(ws + alloc((size_t)DD * DD * 2));
    float* isc = (float*)(ws + alloc((size_t)TT * 32 * 4));
    float* osc = (float*)(ws + alloc((size_t)TT * 32 * 4));
    float* wb  = (float*)(ws + alloc((size_t)1560 * 32 * 4));
    float* lb  = (float*)(ws + alloc((size_t)NN * 32 * 4));
    u16* vin = (u16*)(ws + off);
    size_t vbytes = (ws_size > off) ? (ws_size - off) : 0;

    // --- init ---
    hipMemsetAsync(isc, 0, (size_t)TT * 32 * 4, stream);
    hipMemsetAsync(osc, 0, (size_t)TT * 32 * 4, stream);
    build_wcat<<<(2304 * DD + 255) / 256, 256, 0, stream>>>(W1, Wbil, Wcat);
    cvt_k<<<(DD * DD + 255) / 256, 256, 0, stream>>>(W2, W2b, DD * DD);
    cvt_k<<<(NN * 32 * DD + 255) / 256, 256, 0, stream>>>(base, ivb, NN * 32 * DD);
    init_rootb<<<(32 * DD + 255) / 256, 256, 0, stream>>>(ovb, rbias);
    {   // leaf transforms
        int M = NN * 32;
        dim3 g((M + 63) / 64, 18);
        transform_k<<<g, 256, 0, stream>>>(ivb, Wcat, Ub, Vb, IWb, b1, M);
    }

    auto g2grid = [](int Mc) {
        int xb = (Mc + 127) / 128;
        int XB8 = ((xb + 7) / 8) * 8;
        return 3 * XB8;
    };

    // --- inside pass (L=40 root value unused downstream) ---
    for (int L = 2; L <= NN - 1; ++L) {
        int S = L - 1, nb = NN + 1 - L;
        int cellbase = TT - (NN - L + 2) * (NN - L + 1) / 2;
        size_t perbegin = (size_t)S * 32 * DD * 2;
        int GC = (vbytes >= perbegin) ? (int)(vbytes / perbegin) : 1;
        if (GC < 1) GC = 1;
        if (GC > nb) GC = nb;
        for (int g0 = 0; g0 < nb; g0 += GC) {
            int gc = (g0 + GC <= nb) ? GC : (nb - g0);
            int Mc = gc * S * 32;
            u16* vout = (S == 1) ? (ivb + (size_t)(cellbase + g0) * 32 * DD) : vin;
            int NG = g2grid(Mc);
            int nblk = NG + ((g0 == 0) ? nb * 32 : 0);
            level_k<MODE_IN><<<nblk, 512, 0, stream>>>(
                Ub, Vb, W2b, b2, vout, Mc, L, g0, S, NG,
                ivb, IWb, ovb, isc, osc, wb, cellbase * 32);
            if (S > 1)
                reduce_k<<<(gc * 32 * 96 + 255) / 256, 256, 0, stream>>>(
                    vin, wb + (size_t)g0 * S * 32, ivb, (cellbase + g0) * 32, gc * 32, S);
        }
        {   // transform new cells
            int M = nb * 32;
            dim3 g((M + 63) / 64, 18);
            transform_k<<<g, 256, 0, stream>>>(
                ivb + (size_t)cellbase * 32 * DD, Wcat,
                Ub + (size_t)cellbase * 32 * DD, Vb + (size_t)cellbase * 32 * DD,
                IWb + (size_t)cellbase * 32 * DD, b1, M);
        }
    }

    // --- root u_o ---
    {
        dim3 g(1, 6);
        transform_k<<<g, 256, 0, stream>>>(
            ovb + (size_t)819 * 32 * DD, Wcat,
            Ub + (size_t)819 * 32 * DD, nullptr, nullptr, b1, 32);
    }

    // --- outside pass ---
    for (int L = NN - 1; L >= 1; --L) {
        int S = NN - L, nb = NN + 1 - L;
        int cellbase = TT - (NN - L + 2) * (NN - L + 1) / 2;
        size_t perbegin = (size_t)S * 32 * DD * 2;
        int GC = (vbytes >= perbegin) ? (int)(vbytes / perbegin) : 1;
        if (GC < 1) GC = 1;
        if (GC > nb) GC = nb;
        for (int g0 = 0; g0 < nb; g0 += GC) {
            int gc = (g0 + GC <= nb) ? GC : (nb - g0);
            int Mc = gc * S * 32;
            u16* vout = (S == 1) ? (ovb + (size_t)(cellbase + g0) * 32 * DD) : vin;
            int NG = g2grid(Mc);
            int nblk = NG + ((g0 == 0) ? nb * 32 : 0);
            level_k<MODE_OUT><<<nblk, 512, 0, stream>>>(
                Ub, Vb, W2b, b2, vout, Mc, L, g0, S, NG,
                ivb, IWb, ovb, isc, osc, wb, cellbase * 32);
            if (S > 1)
                reduce_k<<<(gc * 32 * 96 + 255) / 256, 256, 0, stream>>>(
                    vin, wb + (size_t)g0 * S * 32, ovb, (cellbase + g0) * 32, gc * 32, S);
        }
        if (L > 1) {   // u_o for new outside cells
            int M = nb * 32;
            dim3 g((M + 63) / 64, 6);
            transform_k<<<g, 256, 0, stream>>>(
                ovb + (size_t)cellbase * 32 * DD, Wcat,
                Ub + (size_t)cellbase * 32 * DD, nullptr, nullptr, b1, M);
        }
    }

    // --- loss ---
    loss_part<<<(NN * 32 + 3) / 4, 256, 0, stream>>>(ovb, base, lb);
    loss_fin<<<1, 256, 0, stream>>>(lb, out);
}

// Round 19
// 4667.759 us; speedup vs baseline: 1.0461x; 1.0303x over previous
//
#include <hip/hip_runtime.h>
#include <math.h>

#define NN 40
#define DD 768
#define TT 820   // (N+1)*N/2

typedef unsigned short u16;
typedef __attribute__((ext_vector_type(8))) short bfrag8;
typedef __attribute__((ext_vector_type(4))) float facc4;

__device__ __forceinline__ int ftd(int b, int e) {
    int l = e - b;
    return TT - (NN - l + 2) * (NN - l + 1) / 2 + b;
}
__device__ __forceinline__ float bf2f(u16 u) {
    union { unsigned int i; float f; } x; x.i = ((unsigned)u) << 16; return x.f;
}
__device__ __forceinline__ u16 f2bf(float f) {
    unsigned u = __float_as_uint(f);
    u += 0x7fff + ((u >> 16) & 1);
    return (u16)(u >> 16);
}
// hardware packed f32->bf16 (RNE), lo in [15:0], hi in [31:16]
__device__ __forceinline__ unsigned cvtpk(float lo, float hi) {
    unsigned r;
    asm("v_cvt_pk_bf16_f32 %0, %1, %2" : "=v"(r) : "v"(lo), "v"(hi));
    return r;
}
__device__ __forceinline__ float dot2(unsigned a, unsigned c) {
    return bf2f((u16)a) * bf2f((u16)c) + bf2f((u16)(a >> 16)) * bf2f((u16)(c >> 16));
}

#define GLOAD16(gp, lp) __builtin_amdgcn_global_load_lds( \
    (const __attribute__((address_space(1))) unsigned int*)(gp), \
    (__attribute__((address_space(3))) unsigned int*)(lp), 16, 0, 0)

#define MODE_IN 1
#define MODE_OUT 2

// map pair-row -> (u cell, v cell)
template<int MODE>
__device__ __forceinline__ void pairmap(int r, int g0, int Sps, int level,
                                        int& uc, int& vc, int& bb)
{
    int p = r >> 5; bb = r & 31;
    int g = g0 + p / Sps, si = p % Sps;
    if (MODE == MODE_IN) {
        int s = si + 1;
        uc = ftd(g, g + s); vc = ftd(g + s, g + level);
    } else {
        if (si < g) { uc = ftd(si, g + level); vc = ftd(si, g); }
        else { int c = si + level + 1; uc = ftd(g, c); vc = ftd(g + level, c); }
    }
}

// ---------------- transform: Out{U,V,W}[m] = A[m] @ Wcat-slab^T (+b1 for V slab) ----------------
// 64-row tiles; single-buffer staging (R16 config — dbuf regressed here: latency-bound,
// fatter LDS hurt mixed-kernel CU packing); source-side swizzle, conflict-free reads.
__global__ __launch_bounds__(256)
void transform_k(const u16* __restrict__ A, const u16* __restrict__ Wcat,
                 u16* __restrict__ OutU, u16* __restrict__ OutV,
                 u16* __restrict__ OutW, const float* __restrict__ bias, int M)
{
    __shared__ __align__(16) u16 As[64 * 32];    // 4 KB
    __shared__ __align__(16) u16 Bs[128 * 32];   // 8 KB
    const int tid = threadIdx.x, lane = tid & 63, wv = tid >> 6;
    const int m0 = blockIdx.x * 64;
    const int slab = blockIdx.y / 6;
    const int j0 = (blockIdx.y % 6) * 128;
    u16* Out = (slab == 0) ? OutU : (slab == 1 ? OutV : OutW);

    const int srow = tid >> 2;          // 0..63
    const int kos = (((tid & 3) ^ ((tid >> 3) & 3))) * 8;   // source-side swizzle
    int ar = m0 + srow; if (ar >= M) ar = M - 1;
    const u16* ap = A + (size_t)ar * DD + kos;
    const u16* bq0 = Wcat + (size_t)(slab * DD + j0 + srow) * DD + kos;
    const u16* bq1 = bq0 + (size_t)64 * DD;
    u16* AsW  = As + wv * 512;
    u16* BsW0 = Bs + wv * 512;  u16* BsW1 = Bs + 2048 + wv * 512;

    facc4 acc[2][4];
    #pragma unroll
    for (int i = 0; i < 2; ++i)
        #pragma unroll
        for (int j = 0; j < 4; ++j) acc[i][j] = (facc4){0.f, 0.f, 0.f, 0.f};

    const int wr = wv >> 1, wc = wv & 1;
    const int fr = lane & 15;
    const int sk = ((lane >> 4) ^ ((lane >> 1) & 3)) * 8;

    for (int k0 = 0; k0 < DD; k0 += 32) {
        GLOAD16(ap + k0, AsW);
        GLOAD16(bq0 + k0, BsW0);
        GLOAD16(bq1 + k0, BsW1);
        __syncthreads();
        bfrag8 a[2], b[4];
        #pragma unroll
        for (int fi = 0; fi < 2; ++fi)
            a[fi] = *(const bfrag8*)&As[(wr * 32 + fi * 16 + fr) * 32 + sk];
        #pragma unroll
        for (int fj = 0; fj < 4; ++fj)
            b[fj] = *(const bfrag8*)&Bs[(wc * 64 + fj * 16 + fr) * 32 + sk];
        #pragma unroll
        for (int fi = 0; fi < 2; ++fi)
            #pragma unroll
            for (int fj = 0; fj < 4; ++fj)
                acc[fi][fj] = __builtin_amdgcn_mfma_f32_16x16x32_bf16(
                    a[fi], b[fj], acc[fi][fj], 0, 0, 0);
        __syncthreads();
    }

    const int r0l = (lane >> 4) * 4;
    #pragma unroll
    for (int fi = 0; fi < 2; ++fi)
        #pragma unroll
        for (int r = 0; r < 4; ++r) {
            int m = m0 + wr * 32 + fi * 16 + r0l + r;
            if (m < M) {
                #pragma unroll
                for (int fj = 0; fj < 4; ++fj) {
                    int n = j0 + wc * 64 + fj * 16 + fr;
                    float vo = acc[fi][fj][r];
                    if (slab == 1) vo += bias[n];   // fold b1 into V
                    Out[(size_t)m * DD + n] = f2bf(vo);
                }
            }
        }
}

// -------- fused level kernel: blocks [0,NG) = UNWEIGHTED gemm2f; blocks [NG,NG+nb*32) = score+softmax --------
// gemm2f: 128M x 256N, 512 thr, dbuf LDS, 1 barrier/K-step, XCD-swizzled, conflict-free swizzle. No setprio.
template<int MODE>
__global__ __launch_bounds__(512)
void level_k(const u16* __restrict__ Ubase, const u16* __restrict__ Vbase,
             const u16* __restrict__ W2, const float* __restrict__ b2,
             u16* __restrict__ Out, int M, int level, int g0, int Sps, int NG,
             const u16* __restrict__ ivb, const u16* __restrict__ IWb,
             const u16* __restrict__ ovb, float* __restrict__ isc,
             float* __restrict__ osc, float* __restrict__ wbuf, int cellrow0)
{
    __shared__ __align__(16) u16 As[2][128 * 32];   // 16 KB
    __shared__ __align__(16) u16 Bs[2][256 * 32];   // 32 KB
    const int tid = threadIdx.x, lane = tid & 63, wv = tid >> 6;

    if (blockIdx.x >= NG) {
        // ---------------- score + softmax block ----------------
        float* sS = (float*)&As[0][0];
        const int blk = blockIdx.x - NG;      // gl*32 + bb
        const int gl = blk >> 5, bb = blk & 31;
        for (int s = wv; s < Sps; s += 8) {
            const u16 *lp, *rp; float add;
            if (MODE == MODE_IN) {
                int lc = ftd(gl, gl + s + 1), rc = ftd(gl + s + 1, gl + level);
                lp = ivb + (size_t)(lc * 32 + bb) * DD;
                rp = IWb + (size_t)(rc * 32 + bb) * DD;
                add = isc[lc * 32 + bb] + isc[rc * 32 + bb];
            } else {
                int pc, scl;
                if (s < gl) { pc = ftd(s, gl + level); scl = ftd(s, gl); }
                else { int c2 = s + level + 1; pc = ftd(gl, c2); scl = ftd(gl + level, c2); }
                lp = ovb + (size_t)(pc * 32 + bb) * DD;
                rp = IWb + (size_t)(scl * 32 + bb) * DD;
                add = osc[pc * 32 + bb] + isc[scl * 32 + bb];
            }
            float sum = 0.f;
            #pragma unroll
            for (int i = 0; i < 3; ++i) {
                uint2 a = *(const uint2*)(lp + i * 256 + lane * 4);
                uint2 c = *(const uint2*)(rp + i * 256 + lane * 4);
                sum += dot2(a.x, c.x) + dot2(a.y, c.y);
            }
            #pragma unroll
            for (int off = 32; off; off >>= 1) sum += __shfl_xor(sum, off);
            if (lane == 0) sS[s] = sum + add;
        }
        __syncthreads();
        if (wv == 0) {
            bool act = lane < Sps;
            float x = act ? sS[lane] : -3.0e38f;
            float m = x;
            #pragma unroll
            for (int off = 32; off; off >>= 1) m = fmaxf(m, __shfl_xor(m, off));
            float e = act ? expf(x - m) : 0.f;
            float ssum = e;
            #pragma unroll
            for (int off = 32; off; off >>= 1) ssum += __shfl_xor(ssum, off);
            float wt = e / ssum;
            if (act) wbuf[(gl * Sps + lane) * 32 + bb] = wt;
            float ws = act ? wt * x : 0.f;
            #pragma unroll
            for (int off = 32; off; off >>= 1) ws += __shfl_xor(ws, off);
            if (lane == 0) {
                float* scout = (MODE == MODE_IN) ? isc : osc;
                scout[cellrow0 + gl * 32 + bb] = ws;
            }
        }
        return;
    }

    // ---------------- gemm2 block (unweighted) ----------------
    const int q = blockIdx.x;
    const int cxcd = q & 7, tq = q >> 3;
    const int mblk = (tq / 3) * 8 + cxcd;
    const int jt = tq % 3;
    const int m0 = mblk * 128;
    if (m0 >= M) return;                     // uniform early-exit (padding blocks)
    const int j0 = jt * 256;

    const int srow = tid >> 2;          // 0..127
    const int ko = (tid & 3) * 8;
    const int aslot = ((tid & 3) ^ ((tid >> 3) & 3)) * 8;
    const int NT = DD / 32;             // 24 K-steps

    const u16 *u0, *v0;
    {
        int r = m0 + srow; if (r >= M) r = M - 1;
        int uc, vc, bb;
        pairmap<MODE>(r, g0, Sps, level, uc, vc, bb);
        u0 = Ubase + (size_t)(uc * 32 + bb) * DD + ko;
        v0 = Vbase + (size_t)(vc * 32 + bb) * DD + ko;
    }

    const int ksrc = ((lane & 3) ^ ((lane >> 3) & 3)) * 8;
    const int brow0 = wv * 16 + (lane >> 2);
    const u16* bsrc0 = W2 + (size_t)(j0 + brow0) * DD + ksrc;
    const u16* bsrc1 = W2 + (size_t)(j0 + 128 + brow0) * DD + ksrc;
    const int bofs0 = wv * 512;
    const int bofs1 = 4096 + wv * 512;

    facc4 acc[4][4];
    #pragma unroll
    for (int i = 0; i < 4; ++i)
        #pragma unroll
        for (int j = 0; j < 4; ++j) acc[i][j] = (facc4){0.f, 0.f, 0.f, 0.f};

    const int wr = wv >> 2, wc = wv & 3;
    const int fr = lane & 15;
    const int sk = ((lane >> 4) ^ ((lane >> 1) & 3)) * 8;

    GLOAD16(bsrc0, &Bs[0][bofs0]);
    GLOAD16(bsrc1, &Bs[0][bofs1]);
    bfrag8 uc_ = *(const bfrag8*)(u0);
    bfrag8 vc_ = *(const bfrag8*)(v0);
    {
        float f[8];
        #pragma unroll
        for (int j = 0; j < 8; ++j)
            f[j] = fmaxf(bf2f((u16)uc_[j]) + bf2f((u16)vc_[j]), 0.f);
        uint4 pk;
        pk.x = cvtpk(f[0], f[1]); pk.y = cvtpk(f[2], f[3]);
        pk.z = cvtpk(f[4], f[5]); pk.w = cvtpk(f[6], f[7]);
        *(uint4*)&As[0][srow * 32 + aslot] = pk;
    }
    bfrag8 un_ = *(const bfrag8*)(u0 + 32);
    bfrag8 vn_ = *(const bfrag8*)(v0 + 32);
    __syncthreads();

    for (int t = 0; t < NT; ++t) {
        const int cur = t & 1;
        if (t + 1 < NT) {
            GLOAD16(bsrc0 + (t + 1) * 32, &Bs[cur ^ 1][bofs0]);
            GLOAD16(bsrc1 + (t + 1) * 32, &Bs[cur ^ 1][bofs1]);
            float f[8];
            #pragma unroll
            for (int j = 0; j < 8; ++j)
                f[j] = fmaxf(bf2f((u16)un_[j]) + bf2f((u16)vn_[j]), 0.f);
            uint4 pk;
            pk.x = cvtpk(f[0], f[1]); pk.y = cvtpk(f[2], f[3]);
            pk.z = cvtpk(f[4], f[5]); pk.w = cvtpk(f[6], f[7]);
            *(uint4*)&As[cur ^ 1][srow * 32 + aslot] = pk;
            if (t + 2 < NT) {
                un_ = *(const bfrag8*)(u0 + (t + 2) * 32);
                vn_ = *(const bfrag8*)(v0 + (t + 2) * 32);
            }
        }
        bfrag8 a[4], b[4];
        #pragma unroll
        for (int fi = 0; fi < 4; ++fi)
            a[fi] = *(const bfrag8*)&As[cur][(wr * 64 + fi * 16 + fr) * 32 + sk];
        #pragma unroll
        for (int fj = 0; fj < 4; ++fj)
            b[fj] = *(const bfrag8*)&Bs[cur][(wc * 64 + fj * 16 + fr) * 32 + sk];
        #pragma unroll
        for (int fi = 0; fi < 4; ++fi)
            #pragma unroll
            for (int fj = 0; fj < 4; ++fj)
                acc[fi][fj] = __builtin_amdgcn_mfma_f32_16x16x32_bf16(
                    a[fi], b[fj], acc[fi][fj], 0, 0, 0);
        __syncthreads();
    }

    const int r0l = (lane >> 4) * 4;
    #pragma unroll
    for (int fi = 0; fi < 4; ++fi)
        #pragma unroll
        for (int r = 0; r < 4; ++r) {
            int m = m0 + wr * 64 + fi * 16 + r0l + r;
            if (m < M) {
                #pragma unroll
                for (int fj = 0; fj < 4; ++fj) {
                    int n = j0 + wc * 64 + fj * 16 + fr;
                    float v = fmaxf(acc[fi][fj][r] + b2[n], 0.f);  // weight applied in reduce
                    Out[(size_t)m * DD + n] = f2bf(v);
                }
            }
        }
}

// ---------------- weighted reduce over splits (8 cols / thread, 4x unroll) ----------------
__global__ __launch_bounds__(256)
void reduce_k(const u16* __restrict__ v, const float* __restrict__ wbuf,
              u16* __restrict__ chart, int cellrow0, int rows, int Sps)
{
    int idx = blockIdx.x * 256 + threadIdx.x;
    int tot = rows * 96;                       // 96 = 768/8
    if (idx >= tot) return;
    int row = idx / 96, c8 = (idx % 96) * 8;   // row = gl*32+bb
    int gl = row >> 5, bb = row & 31;
    const u16* p = v + ((size_t)(gl * Sps) * 32 + bb) * DD + c8;
    const float* wp = wbuf + (size_t)gl * Sps * 32 + bb;
    const size_t st = (size_t)32 * DD;
    float a0[8] = {}, a1[8] = {}, a2[8] = {}, a3[8] = {};
    int s = 0;
    for (; s + 4 <= Sps; s += 4) {
        bfrag8 x0 = *(const bfrag8*)(p + (size_t)(s + 0) * st);
        bfrag8 x1 = *(const bfrag8*)(p + (size_t)(s + 1) * st);
        bfrag8 x2 = *(const bfrag8*)(p + (size_t)(s + 2) * st);
        bfrag8 x3 = *(const bfrag8*)(p + (size_t)(s + 3) * st);
        float w0 = wp[(size_t)(s + 0) * 32];
        float w1 = wp[(size_t)(s + 1) * 32];
        float w2 = wp[(size_t)(s + 2) * 32];
        float w3 = wp[(size_t)(s + 3) * 32];
        #pragma unroll
        for (int j = 0; j < 8; ++j) {
            a0[j] += w0 * bf2f((u16)x0[j]);
            a1[j] += w1 * bf2f((u16)x1[j]);
            a2[j] += w2 * bf2f((u16)x2[j]);
            a3[j] += w3 * bf2f((u16)x3[j]);
        }
    }
    for (; s < Sps; ++s) {
        bfrag8 x = *(const bfrag8*)(p + (size_t)s * st);
        float w = wp[(size_t)s * 32];
        #pragma unroll
        for (int j = 0; j < 8; ++j) a0[j] += w * bf2f((u16)x[j]);
    }
    #pragma unroll
    for (int j = 0; j < 8; ++j) a0[j] += (a1[j] + a2[j]) + a3[j];
    uint4 pk;
    pk.x = cvtpk(a0[0], a0[1]); pk.y = cvtpk(a0[2], a0[3]);
    pk.z = cvtpk(a0[4], a0[5]); pk.w = cvtpk(a0[6], a0[7]);
    *(uint4*)&chart[(size_t)(cellrow0 + row) * DD + c8] = pk;
}

// ---------------- loss ----------------
__global__ __launch_bounds__(256)
void loss_part(const u16* __restrict__ ovb, const float* __restrict__ base,
               float* __restrict__ lb)
{
    int wid = (blockIdx.x * 256 + threadIdx.x) >> 6;
    int lane = threadIdx.x & 63;
    if (wid >= NN * 32) return;
    const u16* t = ovb + (size_t)wid * DD;
    const float* b = base + (size_t)wid * DD;
    float num = 0, nt = 0, nb = 0;
    #pragma unroll
    for (int i = 0; i < 3; ++i) {
        uint2 a2 = *(const uint2*)(t + i * 256 + lane * 4);
        float4 c = *(const float4*)(b + i * 256 + lane * 4);
        float a0 = bf2f((u16)a2.x), a1 = bf2f((u16)(a2.x >> 16));
        float a2f = bf2f((u16)a2.y), a3 = bf2f((u16)(a2.y >> 16));
        num += a0 * c.x + a1 * c.y + a2f * c.z + a3 * c.w;
        nt  += a0 * a0 + a1 * a1 + a2f * a2f + a3 * a3;
        nb  += c.x * c.x + c.y * c.y + c.z * c.z + c.w * c.w;
    }
    #pragma unroll
    for (int off = 32; off; off >>= 1) {
        num += __shfl_down(num, off);
        nt  += __shfl_down(nt, off);
        nb  += __shfl_down(nb, off);
    }
    if (lane == 0) {
        float den = fmaxf(sqrtf(nt) * sqrtf(nb), 1e-8f);
        lb[wid] = 1.f - num / den;
    }
}

__global__ void loss_fin(const float* __restrict__ lb, float* __restrict__ out)
{
    __shared__ float red[256];
    float s = 0;
    for (int i = threadIdx.x; i < NN * 32; i += 256) s += lb[i];
    red[threadIdx.x] = s;
    __syncthreads();
    for (int o = 128; o; o >>= 1) {
        if (threadIdx.x < o) red[threadIdx.x] += red[threadIdx.x + o];
        __syncthreads();
    }
    if (threadIdx.x == 0) out[0] = red[0] / (NN * 32.f);
}

// ---------------- init helpers ----------------
__global__ void build_wcat(const float* __restrict__ W1, const float* __restrict__ Wbil,
                           u16* __restrict__ Wcat)
{
    int idx = blockIdx.x * 256 + threadIdx.x;
    if (idx >= 2304 * DD) return;
    int r = idx / DD, k = idx % DD;
    float v;
    if (r < 768) v = W1[(size_t)r * 1536 + k];
    else if (r < 1536) v = W1[(size_t)(r - 768) * 1536 + 768 + k];
    else v = Wbil[(size_t)(r - 1536) * DD + k];
    Wcat[idx] = f2bf(v);
}

__global__ void cvt_k(const float* __restrict__ in, u16* __restrict__ out, int n)
{
    int idx = blockIdx.x * 256 + threadIdx.x;
    if (idx < n) out[idx] = f2bf(in[idx]);
}

__global__ void init_rootb(u16* __restrict__ ovb, const float* __restrict__ rb)
{
    int idx = blockIdx.x * 256 + threadIdx.x;
    if (idx < 32 * DD) ovb[(size_t)819 * 32 * DD + idx] = f2bf(rb[idx % DD]);
}

extern "C" void kernel_launch(void* const* d_in, const int* in_sizes, int n_in,
                              void* d_out, int out_size, void* d_ws, size_t ws_size,
                              hipStream_t stream)
{
    const float* base  = (const float*)d_in[0];
    const float* Wbil  = (const float*)d_in[1];
    const float* W1    = (const float*)d_in[2];
    const float* b1    = (const float*)d_in[3];
    const float* W2    = (const float*)d_in[4];
    const float* b2    = (const float*)d_in[5];
    const float* rbias = (const float*)d_in[6];
    float* out = (float*)d_out;

    char* ws = (char*)d_ws;
    size_t off = 0;
    auto alloc = [&](size_t bytes) { size_t o = off; off = (off + bytes + 255) & ~(size_t)255; return o; };
    const size_t SB = (size_t)TT * 32 * DD * 2;   // 40.3 MB bf16 per chart slab
    u16*  ivb = (u16*)(ws + alloc(SB));
    u16*  ovb = (u16*)(ws + alloc(SB));
    u16*  Ub  = (u16*)(ws + alloc(SB));
    u16*  Vb  = (u16*)(ws + alloc(SB));
    u16*  IWb = (u16*)(ws + alloc(SB));
    u16*  Wcat = (u16*)(ws + alloc((size_t)2304 * DD * 2));
    u16*  W2b  = (u16*)(ws + alloc((size_t)DD * DD * 2));
    float* isc = (float*)(ws + alloc((size_t)TT * 32 * 4));
    float* osc = (float*)(ws + alloc((size_t)TT * 32 * 4));
    float* wb  = (float*)(ws + alloc((size_t)1560 * 32 * 4));
    float* lb  = (float*)(ws + alloc((size_t)NN * 32 * 4));
    u16* vin = (u16*)(ws + off);
    size_t vbytes = (ws_size > off) ? (ws_size - off) : 0;

    // --- init ---
    hipMemsetAsync(isc, 0, (size_t)TT * 32 * 4, stream);
    hipMemsetAsync(osc, 0, (size_t)TT * 32 * 4, stream);
    build_wcat<<<(2304 * DD + 255) / 256, 256, 0, stream>>>(W1, Wbil, Wcat);
    cvt_k<<<(DD * DD + 255) / 256, 256, 0, stream>>>(W2, W2b, DD * DD);
    cvt_k<<<(NN * 32 * DD + 255) / 256, 256, 0, stream>>>(base, ivb, NN * 32 * DD);
    init_rootb<<<(32 * DD + 255) / 256, 256, 0, stream>>>(ovb, rbias);
    {   // leaf transforms
        int M = NN * 32;
        dim3 g((M + 63) / 64, 18);
        transform_k<<<g, 256, 0, stream>>>(ivb, Wcat, Ub, Vb, IWb, b1, M);
    }

    auto g2grid = [](int Mc) {
        int xb = (Mc + 127) / 128;
        int XB8 = ((xb + 7) / 8) * 8;
        return 3 * XB8;
    };

    // --- inside pass (L=40 root value unused downstream) ---
    for (int L = 2; L <= NN - 1; ++L) {
        int S = L - 1, nb = NN + 1 - L;
        int cellbase = TT - (NN - L + 2) * (NN - L + 1) / 2;
        size_t perbegin = (size_t)S * 32 * DD * 2;
        int GC = (vbytes >= perbegin) ? (int)(vbytes / perbegin) : 1;
        if (GC < 1) GC = 1;
        if (GC > nb) GC = nb;
        for (int g0 = 0; g0 < nb; g0 += GC) {
            int gc = (g0 + GC <= nb) ? GC : (nb - g0);
            int Mc = gc * S * 32;
            u16* vout = (S == 1) ? (ivb + (size_t)(cellbase + g0) * 32 * DD) : vin;
            int NG = g2grid(Mc);
            int nblk = NG + ((g0 == 0) ? nb * 32 : 0);
            level_k<MODE_IN><<<nblk, 512, 0, stream>>>(
                Ub, Vb, W2b, b2, vout, Mc, L, g0, S, NG,
                ivb, IWb, ovb, isc, osc, wb, cellbase * 32);
            if (S > 1)
                reduce_k<<<(gc * 32 * 96 + 255) / 256, 256, 0, stream>>>(
                    vin, wb + (size_t)g0 * S * 32, ivb, (cellbase + g0) * 32, gc * 32, S);
        }
        {   // transform new cells
            int M = nb * 32;
            dim3 g((M + 63) / 64, 18);
            transform_k<<<g, 256, 0, stream>>>(
                ivb + (size_t)cellbase * 32 * DD, Wcat,
                Ub + (size_t)cellbase * 32 * DD, Vb + (size_t)cellbase * 32 * DD,
                IWb + (size_t)cellbase * 32 * DD, b1, M);
        }
    }

    // --- root u_o ---
    {
        dim3 g(1, 6);
        transform_k<<<g, 256, 0, stream>>>(
            ovb + (size_t)819 * 32 * DD, Wcat,
            Ub + (size_t)819 * 32 * DD, nullptr, nullptr, b1, 32);
    }

    // --- outside pass ---
    for (int L = NN - 1; L >= 1; --L) {
        int S = NN - L, nb = NN + 1 - L;
        int cellbase = TT - (NN - L + 2) * (NN - L + 1) / 2;
        size_t perbegin = (size_t)S * 32 * DD * 2;
        int GC = (vbytes >= perbegin) ? (int)(vbytes / perbegin) : 1;
        if (GC < 1) GC = 1;
        if (GC > nb) GC = nb;
        for (int g0 = 0; g0 < nb; g0 += GC) {
            int gc = (g0 + GC <= nb) ? GC : (nb - g0);
            int Mc = gc * S * 32;
            u16* vout = (S == 1) ? (ovb + (size_t)(cellbase + g0) * 32 * DD) : vin;
            int NG = g2grid(Mc);
            int nblk = NG + ((g0 == 0) ? nb * 32 : 0);
            level_k<MODE_OUT><<<nblk, 512, 0, stream>>>(
                Ub, Vb, W2b, b2, vout, Mc, L, g0, S, NG,
                ivb, IWb, ovb, isc, osc, wb, cellbase * 32);
            if (S > 1)
                reduce_k<<<(gc * 32 * 96 + 255) / 256, 256, 0, stream>>>(
                    vin, wb + (size_t)g0 * S * 32, ovb, (cellbase + g0) * 32, gc * 32, S);
        }
        if (L > 1) {   // u_o for new outside cells
            int M = nb * 32;
            dim3 g((M + 63) / 64, 6);
            transform_k<<<g, 256, 0, stream>>>(
                ovb + (size_t)cellbase * 32 * DD, Wcat,
                Ub + (size_t)cellbase * 32 * DD, nullptr, nullptr, b1, M);
        }
    }

    // --- loss ---
    loss_part<<<(NN * 32 + 3) / 4, 256, 0, stream>>>(ovb, base, lb);
    loss_fin<<<1, 256, 0, stream>>>(lb, out);
}

// Round 20
// 4362.174 us; speedup vs baseline: 1.1194x; 1.0701x over previous
//
#include <hip/hip_runtime.h>
#include <math.h>

#define NN 40
#define DD 768
#define TT 820   // (N+1)*N/2

typedef unsigned short u16;
typedef __attribute__((ext_vector_type(8))) short bfrag8;
typedef __attribute__((ext_vector_type(4))) float facc4;

__device__ __forceinline__ int ftd(int b, int e) {
    int l = e - b;
    return TT - (NN - l + 2) * (NN - l + 1) / 2 + b;
}
__device__ __forceinline__ float bf2f(u16 u) {
    union { unsigned int i; float f; } x; x.i = ((unsigned)u) << 16; return x.f;
}
__device__ __forceinline__ u16 f2bf(float f) {
    unsigned u = __float_as_uint(f);
    u += 0x7fff + ((u >> 16) & 1);
    return (u16)(u >> 16);
}
// hardware packed f32->bf16 (RNE), lo in [15:0], hi in [31:16]
__device__ __forceinline__ unsigned cvtpk(float lo, float hi) {
    unsigned r;
    asm("v_cvt_pk_bf16_f32 %0, %1, %2" : "=v"(r) : "v"(lo), "v"(hi));
    return r;
}
__device__ __forceinline__ float dot2(unsigned a, unsigned c) {
    return bf2f((u16)a) * bf2f((u16)c) + bf2f((u16)(a >> 16)) * bf2f((u16)(c >> 16));
}

#define GLOAD16(gp, lp) __builtin_amdgcn_global_load_lds( \
    (const __attribute__((address_space(1))) unsigned int*)(gp), \
    (__attribute__((address_space(3))) unsigned int*)(lp), 16, 0, 0)

#define MODE_IN 1
#define MODE_OUT 2

// map pair-row -> (u cell, v cell)
template<int MODE>
__device__ __forceinline__ void pairmap(int r, int g0, int Sps, int level,
                                        int& uc, int& vc, int& bb)
{
    int p = r >> 5; bb = r & 31;
    int g = g0 + p / Sps, si = p % Sps;
    if (MODE == MODE_IN) {
        int s = si + 1;
        uc = ftd(g, g + s); vc = ftd(g + s, g + level);
    } else {
        if (si < g) { uc = ftd(si, g + level); vc = ftd(si, g); }
        else { int c = si + level + 1; uc = ftd(g, c); vc = ftd(g + level, c); }
    }
}

// ---------------- transform: Out{U,V,W}[m] = A[m] @ Wcat-slab^T (+b1 for V slab) ----------------
// 64x64 tiles (latency-bound dispatches: 2x blocks for fill); single-buffer staging,
// source-side swizzle, conflict-free reads. Wave tile 32x32, acc 2x2.
__global__ __launch_bounds__(256)
void transform_k(const u16* __restrict__ A, const u16* __restrict__ Wcat,
                 u16* __restrict__ OutU, u16* __restrict__ OutV,
                 u16* __restrict__ OutW, const float* __restrict__ bias, int M)
{
    __shared__ __align__(16) u16 As[64 * 32];    // 4 KB
    __shared__ __align__(16) u16 Bs[64 * 32];    // 4 KB
    const int tid = threadIdx.x, lane = tid & 63, wv = tid >> 6;
    const int m0 = blockIdx.x * 64;
    const int slab = blockIdx.y / 12;
    const int j0 = (blockIdx.y % 12) * 64;
    u16* Out = (slab == 0) ? OutU : (slab == 1 ? OutV : OutW);

    const int srow = tid >> 2;          // 0..63
    const int kos = (((tid & 3) ^ ((tid >> 3) & 3))) * 8;   // source-side swizzle
    int ar = m0 + srow; if (ar >= M) ar = M - 1;
    const u16* ap = A + (size_t)ar * DD + kos;
    const u16* bq = Wcat + (size_t)(slab * DD + j0 + srow) * DD + kos;
    u16* AsW = As + wv * 512;
    u16* BsW = Bs + wv * 512;

    facc4 acc[2][2];
    #pragma unroll
    for (int i = 0; i < 2; ++i)
        #pragma unroll
        for (int j = 0; j < 2; ++j) acc[i][j] = (facc4){0.f, 0.f, 0.f, 0.f};

    const int wr = wv >> 1, wc = wv & 1;        // 2x2 wave grid; wave = 32 x 32
    const int fr = lane & 15;
    const int sk = ((lane >> 4) ^ ((lane >> 1) & 3)) * 8;

    for (int k0 = 0; k0 < DD; k0 += 32) {
        GLOAD16(ap + k0, AsW);
        GLOAD16(bq + k0, BsW);
        __syncthreads();
        bfrag8 a[2], b[2];
        #pragma unroll
        for (int fi = 0; fi < 2; ++fi)
            a[fi] = *(const bfrag8*)&As[(wr * 32 + fi * 16 + fr) * 32 + sk];
        #pragma unroll
        for (int fj = 0; fj < 2; ++fj)
            b[fj] = *(const bfrag8*)&Bs[(wc * 32 + fj * 16 + fr) * 32 + sk];
        #pragma unroll
        for (int fi = 0; fi < 2; ++fi)
            #pragma unroll
            for (int fj = 0; fj < 2; ++fj)
                acc[fi][fj] = __builtin_amdgcn_mfma_f32_16x16x32_bf16(
                    a[fi], b[fj], acc[fi][fj], 0, 0, 0);
        __syncthreads();
    }

    const int r0l = (lane >> 4) * 4;
    #pragma unroll
    for (int fi = 0; fi < 2; ++fi)
        #pragma unroll
        for (int r = 0; r < 4; ++r) {
            int m = m0 + wr * 32 + fi * 16 + r0l + r;
            if (m < M) {
                #pragma unroll
                for (int fj = 0; fj < 2; ++fj) {
                    int n = j0 + wc * 32 + fj * 16 + fr;
                    float vo = acc[fi][fj][r];
                    if (slab == 1) vo += bias[n];   // fold b1 into V
                    Out[(size_t)m * DD + n] = f2bf(vo);
                }
            }
        }
}

// -------- fused level kernel: blocks [0,NG) = UNWEIGHTED gemm2f; blocks [NG,NG+nb*32) = score+softmax --------
// gemm2f: 128M x 256N, 512 thr, dbuf LDS, 1 barrier/K-step, XCD-swizzled, conflict-free swizzle. No setprio.
template<int MODE>
__global__ __launch_bounds__(512)
void level_k(const u16* __restrict__ Ubase, const u16* __restrict__ Vbase,
             const u16* __restrict__ W2, const float* __restrict__ b2,
             u16* __restrict__ Out, int M, int level, int g0, int Sps, int NG,
             const u16* __restrict__ ivb, const u16* __restrict__ IWb,
             const u16* __restrict__ ovb, float* __restrict__ isc,
             float* __restrict__ osc, float* __restrict__ wbuf, int cellrow0)
{
    __shared__ __align__(16) u16 As[2][128 * 32];   // 16 KB
    __shared__ __align__(16) u16 Bs[2][256 * 32];   // 32 KB
    const int tid = threadIdx.x, lane = tid & 63, wv = tid >> 6;

    if (blockIdx.x >= NG) {
        // ---------------- score + softmax block ----------------
        float* sS = (float*)&As[0][0];
        const int blk = blockIdx.x - NG;      // gl*32 + bb
        const int gl = blk >> 5, bb = blk & 31;
        for (int s = wv; s < Sps; s += 8) {
            const u16 *lp, *rp; float add;
            if (MODE == MODE_IN) {
                int lc = ftd(gl, gl + s + 1), rc = ftd(gl + s + 1, gl + level);
                lp = ivb + (size_t)(lc * 32 + bb) * DD;
                rp = IWb + (size_t)(rc * 32 + bb) * DD;
                add = isc[lc * 32 + bb] + isc[rc * 32 + bb];
            } else {
                int pc, scl;
                if (s < gl) { pc = ftd(s, gl + level); scl = ftd(s, gl); }
                else { int c2 = s + level + 1; pc = ftd(gl, c2); scl = ftd(gl + level, c2); }
                lp = ovb + (size_t)(pc * 32 + bb) * DD;
                rp = IWb + (size_t)(scl * 32 + bb) * DD;
                add = osc[pc * 32 + bb] + isc[scl * 32 + bb];
            }
            float sum = 0.f;
            #pragma unroll
            for (int i = 0; i < 3; ++i) {
                uint2 a = *(const uint2*)(lp + i * 256 + lane * 4);
                uint2 c = *(const uint2*)(rp + i * 256 + lane * 4);
                sum += dot2(a.x, c.x) + dot2(a.y, c.y);
            }
            #pragma unroll
            for (int off = 32; off; off >>= 1) sum += __shfl_xor(sum, off);
            if (lane == 0) sS[s] = sum + add;
        }
        __syncthreads();
        if (wv == 0) {
            bool act = lane < Sps;
            float x = act ? sS[lane] : -3.0e38f;
            float m = x;
            #pragma unroll
            for (int off = 32; off; off >>= 1) m = fmaxf(m, __shfl_xor(m, off));
            float e = act ? expf(x - m) : 0.f;
            float ssum = e;
            #pragma unroll
            for (int off = 32; off; off >>= 1) ssum += __shfl_xor(ssum, off);
            float wt = e / ssum;
            if (act) wbuf[(gl * Sps + lane) * 32 + bb] = wt;
            float ws = act ? wt * x : 0.f;
            #pragma unroll
            for (int off = 32; off; off >>= 1) ws += __shfl_xor(ws, off);
            if (lane == 0) {
                float* scout = (MODE == MODE_IN) ? isc : osc;
                scout[cellrow0 + gl * 32 + bb] = ws;
            }
        }
        return;
    }

    // ---------------- gemm2 block (unweighted) ----------------
    const int q = blockIdx.x;
    const int cxcd = q & 7, tq = q >> 3;
    const int mblk = (tq / 3) * 8 + cxcd;
    const int jt = tq % 3;
    const int m0 = mblk * 128;
    if (m0 >= M) return;                     // uniform early-exit (padding blocks)
    const int j0 = jt * 256;

    const int srow = tid >> 2;          // 0..127
    const int ko = (tid & 3) * 8;
    const int aslot = ((tid & 3) ^ ((tid >> 3) & 3)) * 8;
    const int NT = DD / 32;             // 24 K-steps

    const u16 *u0, *v0;
    {
        int r = m0 + srow; if (r >= M) r = M - 1;
        int uc, vc, bb;
        pairmap<MODE>(r, g0, Sps, level, uc, vc, bb);
        u0 = Ubase + (size_t)(uc * 32 + bb) * DD + ko;
        v0 = Vbase + (size_t)(vc * 32 + bb) * DD + ko;
    }

    const int ksrc = ((lane & 3) ^ ((lane >> 3) & 3)) * 8;
    const int brow0 = wv * 16 + (lane >> 2);
    const u16* bsrc0 = W2 + (size_t)(j0 + brow0) * DD + ksrc;
    const u16* bsrc1 = W2 + (size_t)(j0 + 128 + brow0) * DD + ksrc;
    const int bofs0 = wv * 512;
    const int bofs1 = 4096 + wv * 512;

    facc4 acc[4][4];
    #pragma unroll
    for (int i = 0; i < 4; ++i)
        #pragma unroll
        for (int j = 0; j < 4; ++j) acc[i][j] = (facc4){0.f, 0.f, 0.f, 0.f};

    const int wr = wv >> 2, wc = wv & 3;
    const int fr = lane & 15;
    const int sk = ((lane >> 4) ^ ((lane >> 1) & 3)) * 8;

    GLOAD16(bsrc0, &Bs[0][bofs0]);
    GLOAD16(bsrc1, &Bs[0][bofs1]);
    bfrag8 uc_ = *(const bfrag8*)(u0);
    bfrag8 vc_ = *(const bfrag8*)(v0);
    {
        float f[8];
        #pragma unroll
        for (int j = 0; j < 8; ++j)
            f[j] = fmaxf(bf2f((u16)uc_[j]) + bf2f((u16)vc_[j]), 0.f);
        uint4 pk;
        pk.x = cvtpk(f[0], f[1]); pk.y = cvtpk(f[2], f[3]);
        pk.z = cvtpk(f[4], f[5]); pk.w = cvtpk(f[6], f[7]);
        *(uint4*)&As[0][srow * 32 + aslot] = pk;
    }
    bfrag8 un_ = *(const bfrag8*)(u0 + 32);
    bfrag8 vn_ = *(const bfrag8*)(v0 + 32);
    __syncthreads();

    for (int t = 0; t < NT; ++t) {
        const int cur = t & 1;
        if (t + 1 < NT) {
            GLOAD16(bsrc0 + (t + 1) * 32, &Bs[cur ^ 1][bofs0]);
            GLOAD16(bsrc1 + (t + 1) * 32, &Bs[cur ^ 1][bofs1]);
            float f[8];
            #pragma unroll
            for (int j = 0; j < 8; ++j)
                f[j] = fmaxf(bf2f((u16)un_[j]) + bf2f((u16)vn_[j]), 0.f);
            uint4 pk;
            pk.x = cvtpk(f[0], f[1]); pk.y = cvtpk(f[2], f[3]);
            pk.z = cvtpk(f[4], f[5]); pk.w = cvtpk(f[6], f[7]);
            *(uint4*)&As[cur ^ 1][srow * 32 + aslot] = pk;
            if (t + 2 < NT) {
                un_ = *(const bfrag8*)(u0 + (t + 2) * 32);
                vn_ = *(const bfrag8*)(v0 + (t + 2) * 32);
            }
        }
        bfrag8 a[4], b[4];
        #pragma unroll
        for (int fi = 0; fi < 4; ++fi)
            a[fi] = *(const bfrag8*)&As[cur][(wr * 64 + fi * 16 + fr) * 32 + sk];
        #pragma unroll
        for (int fj = 0; fj < 4; ++fj)
            b[fj] = *(const bfrag8*)&Bs[cur][(wc * 64 + fj * 16 + fr) * 32 + sk];
        #pragma unroll
        for (int fi = 0; fi < 4; ++fi)
            #pragma unroll
            for (int fj = 0; fj < 4; ++fj)
                acc[fi][fj] = __builtin_amdgcn_mfma_f32_16x16x32_bf16(
                    a[fi], b[fj], acc[fi][fj], 0, 0, 0);
        __syncthreads();
    }

    const int r0l = (lane >> 4) * 4;
    #pragma unroll
    for (int fi = 0; fi < 4; ++fi)
        #pragma unroll
        for (int r = 0; r < 4; ++r) {
            int m = m0 + wr * 64 + fi * 16 + r0l + r;
            if (m < M) {
                #pragma unroll
                for (int fj = 0; fj < 4; ++fj) {
                    int n = j0 + wc * 64 + fj * 16 + fr;
                    float v = fmaxf(acc[fi][fj][r] + b2[n], 0.f);  // weight applied in reduce
                    Out[(size_t)m * DD + n] = f2bf(v);
                }
            }
        }
}

// ---------------- weighted reduce over splits (8 cols / thread, 4x unroll) ----------------
__global__ __launch_bounds__(256)
void reduce_k(const u16* __restrict__ v, const float* __restrict__ wbuf,
              u16* __restrict__ chart, int cellrow0, int rows, int Sps)
{
    int idx = blockIdx.x * 256 + threadIdx.x;
    int tot = rows * 96;                       // 96 = 768/8
    if (idx >= tot) return;
    int row = idx / 96, c8 = (idx % 96) * 8;   // row = gl*32+bb
    int gl = row >> 5, bb = row & 31;
    const u16* p = v + ((size_t)(gl * Sps) * 32 + bb) * DD + c8;
    const float* wp = wbuf + (size_t)gl * Sps * 32 + bb;
    const size_t st = (size_t)32 * DD;
    float a0[8] = {}, a1[8] = {}, a2[8] = {}, a3[8] = {};
    int s = 0;
    for (; s + 4 <= Sps; s += 4) {
        bfrag8 x0 = *(const bfrag8*)(p + (size_t)(s + 0) * st);
        bfrag8 x1 = *(const bfrag8*)(p + (size_t)(s + 1) * st);
        bfrag8 x2 = *(const bfrag8*)(p + (size_t)(s + 2) * st);
        bfrag8 x3 = *(const bfrag8*)(p + (size_t)(s + 3) * st);
        float w0 = wp[(size_t)(s + 0) * 32];
        float w1 = wp[(size_t)(s + 1) * 32];
        float w2 = wp[(size_t)(s + 2) * 32];
        float w3 = wp[(size_t)(s + 3) * 32];
        #pragma unroll
        for (int j = 0; j < 8; ++j) {
            a0[j] += w0 * bf2f((u16)x0[j]);
            a1[j] += w1 * bf2f((u16)x1[j]);
            a2[j] += w2 * bf2f((u16)x2[j]);
            a3[j] += w3 * bf2f((u16)x3[j]);
        }
    }
    for (; s < Sps; ++s) {
        bfrag8 x = *(const bfrag8*)(p + (size_t)s * st);
        float w = wp[(size_t)s * 32];
        #pragma unroll
        for (int j = 0; j < 8; ++j) a0[j] += w * bf2f((u16)x[j]);
    }
    #pragma unroll
    for (int j = 0; j < 8; ++j) a0[j] += (a1[j] + a2[j]) + a3[j];
    uint4 pk;
    pk.x = cvtpk(a0[0], a0[1]); pk.y = cvtpk(a0[2], a0[3]);
    pk.z = cvtpk(a0[4], a0[5]); pk.w = cvtpk(a0[6], a0[7]);
    *(uint4*)&chart[(size_t)(cellrow0 + row) * DD + c8] = pk;
}

// ---------------- loss ----------------
__global__ __launch_bounds__(256)
void loss_part(const u16* __restrict__ ovb, const float* __restrict__ base,
               float* __restrict__ lb)
{
    int wid = (blockIdx.x * 256 + threadIdx.x) >> 6;
    int lane = threadIdx.x & 63;
    if (wid >= NN * 32) return;
    const u16* t = ovb + (size_t)wid * DD;
    const float* b = base + (size_t)wid * DD;
    float num = 0, nt = 0, nb = 0;
    #pragma unroll
    for (int i = 0; i < 3; ++i) {
        uint2 a2 = *(const uint2*)(t + i * 256 + lane * 4);
        float4 c = *(const float4*)(b + i * 256 + lane * 4);
        float a0 = bf2f((u16)a2.x), a1 = bf2f((u16)(a2.x >> 16));
        float a2f = bf2f((u16)a2.y), a3 = bf2f((u16)(a2.y >> 16));
        num += a0 * c.x + a1 * c.y + a2f * c.z + a3 * c.w;
        nt  += a0 * a0 + a1 * a1 + a2f * a2f + a3 * a3;
        nb  += c.x * c.x + c.y * c.y + c.z * c.z + c.w * c.w;
    }
    #pragma unroll
    for (int off = 32; off; off >>= 1) {
        num += __shfl_down(num, off);
        nt  += __shfl_down(nt, off);
        nb  += __shfl_down(nb, off);
    }
    if (lane == 0) {
        float den = fmaxf(sqrtf(nt) * sqrtf(nb), 1e-8f);
        lb[wid] = 1.f - num / den;
    }
}

__global__ void loss_fin(const float* __restrict__ lb, float* __restrict__ out)
{
    __shared__ float red[256];
    float s = 0;
    for (int i = threadIdx.x; i < NN * 32; i += 256) s += lb[i];
    red[threadIdx.x] = s;
    __syncthreads();
    for (int o = 128; o; o >>= 1) {
        if (threadIdx.x < o) red[threadIdx.x] += red[threadIdx.x + o];
        __syncthreads();
    }
    if (threadIdx.x == 0) out[0] = red[0] / (NN * 32.f);
}

// ---------------- init helpers ----------------
__global__ void build_wcat(const float* __restrict__ W1, const float* __restrict__ Wbil,
                           u16* __restrict__ Wcat)
{
    int idx = blockIdx.x * 256 + threadIdx.x;
    if (idx >= 2304 * DD) return;
    int r = idx / DD, k = idx % DD;
    float v;
    if (r < 768) v = W1[(size_t)r * 1536 + k];
    else if (r < 1536) v = W1[(size_t)(r - 768) * 1536 + 768 + k];
    else v = Wbil[(size_t)(r - 1536) * DD + k];
    Wcat[idx] = f2bf(v);
}

__global__ void cvt_k(const float* __restrict__ in, u16* __restrict__ out, int n)
{
    int idx = blockIdx.x * 256 + threadIdx.x;
    if (idx < n) out[idx] = f2bf(in[idx]);
}

__global__ void init_rootb(u16* __restrict__ ovb, const float* __restrict__ rb)
{
    int idx = blockIdx.x * 256 + threadIdx.x;
    if (idx < 32 * DD) ovb[(size_t)819 * 32 * DD + idx] = f2bf(rb[idx % DD]);
}

extern "C" void kernel_launch(void* const* d_in, const int* in_sizes, int n_in,
                              void* d_out, int out_size, void* d_ws, size_t ws_size,
                              hipStream_t stream)
{
    const float* base  = (const float*)d_in[0];
    const float* Wbil  = (const float*)d_in[1];
    const float* W1    = (const float*)d_in[2];
    const float* b1    = (const float*)d_in[3];
    const float* W2    = (const float*)d_in[4];
    const float* b2    = (const float*)d_in[5];
    const float* rbias = (const float*)d_in[6];
    float* out = (float*)d_out;

    char* ws = (char*)d_ws;
    size_t off = 0;
    auto alloc = [&](size_t bytes) { size_t o = off; off = (off + bytes + 255) & ~(size_t)255; return o; };
    const size_t SB = (size_t)TT * 32 * DD * 2;   // 40.3 MB bf16 per chart slab
    u16*  ivb = (u16*)(ws + alloc(SB));
    u16*  ovb = (u16*)(ws + alloc(SB));
    u16*  Ub  = (u16*)(ws + alloc(SB));
    u16*  Vb  = (u16*)(ws + alloc(SB));
    u16*  IWb = (u16*)(ws + alloc(SB));
    u16*  Wcat = (u16*)(ws + alloc((size_t)2304 * DD * 2));
    u16*  W2b  = (u16*)(ws + alloc((size_t)DD * DD * 2));
    float* isc = (float*)(ws + alloc((size_t)TT * 32 * 4));
    float* osc = (float*)(ws + alloc((size_t)TT * 32 * 4));
    float* wb  = (float*)(ws + alloc((size_t)1560 * 32 * 4));
    float* lb  = (float*)(ws + alloc((size_t)NN * 32 * 4));
    u16* vin = (u16*)(ws + off);
    size_t vbytes = (ws_size > off) ? (ws_size - off) : 0;

    // --- init ---
    hipMemsetAsync(isc, 0, (size_t)TT * 32 * 4, stream);
    hipMemsetAsync(osc, 0, (size_t)TT * 32 * 4, stream);
    build_wcat<<<(2304 * DD + 255) / 256, 256, 0, stream>>>(W1, Wbil, Wcat);
    cvt_k<<<(DD * DD + 255) / 256, 256, 0, stream>>>(W2, W2b, DD * DD);
    cvt_k<<<(NN * 32 * DD + 255) / 256, 256, 0, stream>>>(base, ivb, NN * 32 * DD);
    init_rootb<<<(32 * DD + 255) / 256, 256, 0, stream>>>(ovb, rbias);
    {   // leaf transforms
        int M = NN * 32;
        dim3 g((M + 63) / 64, 36);
        transform_k<<<g, 256, 0, stream>>>(ivb, Wcat, Ub, Vb, IWb, b1, M);
    }

    auto g2grid = [](int Mc) {
        int xb = (Mc + 127) / 128;
        int XB8 = ((xb + 7) / 8) * 8;
        return 3 * XB8;
    };

    // --- inside pass (L=40 root value unused downstream) ---
    for (int L = 2; L <= NN - 1; ++L) {
        int S = L - 1, nb = NN + 1 - L;
        int cellbase = TT - (NN - L + 2) * (NN - L + 1) / 2;
        size_t perbegin = (size_t)S * 32 * DD * 2;
        int GC = (vbytes >= perbegin) ? (int)(vbytes / perbegin) : 1;
        if (GC < 1) GC = 1;
        if (GC > nb) GC = nb;
        for (int g0 = 0; g0 < nb; g0 += GC) {
            int gc = (g0 + GC <= nb) ? GC : (nb - g0);
            int Mc = gc * S * 32;
            u16* vout = (S == 1) ? (ivb + (size_t)(cellbase + g0) * 32 * DD) : vin;
            int NG = g2grid(Mc);
            int nblk = NG + ((g0 == 0) ? nb * 32 : 0);
            level_k<MODE_IN><<<nblk, 512, 0, stream>>>(
                Ub, Vb, W2b, b2, vout, Mc, L, g0, S, NG,
                ivb, IWb, ovb, isc, osc, wb, cellbase * 32);
            if (S > 1)
                reduce_k<<<(gc * 32 * 96 + 255) / 256, 256, 0, stream>>>(
                    vin, wb + (size_t)g0 * S * 32, ivb, (cellbase + g0) * 32, gc * 32, S);
        }
        {   // transform new cells
            int M = nb * 32;
            dim3 g((M + 63) / 64, 36);
            transform_k<<<g, 256, 0, stream>>>(
                ivb + (size_t)cellbase * 32 * DD, Wcat,
                Ub + (size_t)cellbase * 32 * DD, Vb + (size_t)cellbase * 32 * DD,
                IWb + (size_t)cellbase * 32 * DD, b1, M);
        }
    }

    // --- root u_o ---
    {
        dim3 g(1, 12);
        transform_k<<<g, 256, 0, stream>>>(
            ovb + (size_t)819 * 32 * DD, Wcat,
            Ub + (size_t)819 * 32 * DD, nullptr, nullptr, b1, 32);
    }

    // --- outside pass ---
    for (int L = NN - 1; L >= 1; --L) {
        int S = NN - L, nb = NN + 1 - L;
        int cellbase = TT - (NN - L + 2) * (NN - L + 1) / 2;
        size_t perbegin = (size_t)S * 32 * DD * 2;
        int GC = (vbytes >= perbegin) ? (int)(vbytes / perbegin) : 1;
        if (GC < 1) GC = 1;
        if (GC > nb) GC = nb;
        for (int g0 = 0; g0 < nb; g0 += GC) {
            int gc = (g0 + GC <= nb) ? GC : (nb - g0);
            int Mc = gc * S * 32;
            u16* vout = (S == 1) ? (ovb + (size_t)(cellbase + g0) * 32 * DD) : vin;
            int NG = g2grid(Mc);
            int nblk = NG + ((g0 == 0) ? nb * 32 : 0);
            level_k<MODE_OUT><<<nblk, 512, 0, stream>>>(
                Ub, Vb, W2b, b2, vout, Mc, L, g0, S, NG,
                ivb, IWb, ovb, isc, osc, wb, cellbase * 32);
            if (S > 1)
                reduce_k<<<(gc * 32 * 96 + 255) / 256, 256, 0, stream>>>(
                    vin, wb + (size_t)g0 * S * 32, ovb, (cellbase + g0) * 32, gc * 32, S);
        }
        if (L > 1) {   // u_o for new outside cells
            int M = nb * 32;
            dim3 g((M + 63) / 64, 12);
            transform_k<<<g, 256, 0, stream>>>(
                ovb + (size_t)cellbase * 32 * DD, Wcat,
                Ub + (size_t)cellbase * 32 * DD, nullptr, nullptr, b1, M);
        }
    }

    // --- loss ---
    loss_part<<<(NN * 32 + 3) / 4, 256, 0, stream>>>(ovb, base, lb);
    loss_fin<<<1, 256, 0, stream>>>(lb, out);
}